// Round 5
// baseline (1077.498 us; speedup 1.0000x reference)
//
#include <hip/hip_runtime.h>
#include <math.h>

#define KSIZE 5
#define KTOT 125

static constexpr float LOWER_CURV = -0.22703196f;
static constexpr float UPPER_CURV = 0.36853024f;

typedef _Float16 h2 __attribute__((ext_vector_type(2)));

__device__ __forceinline__ h2 pack_f16(float a, float b) {
    return __builtin_bit_cast(h2, __builtin_amdgcn_cvt_pkrtz(a, b));
}
__device__ __forceinline__ unsigned pack_u32(float a, float b) {
    return __builtin_bit_cast(unsigned, __builtin_amdgcn_cvt_pkrtz(a, b));
}
__device__ __forceinline__ float fdot2f(h2 a, h2 b, float c) {
#if __has_builtin(__builtin_amdgcn_fdot2)
    return __builtin_amdgcn_fdot2(a, b, c, false);
#else
    return c + (float)a[0] * (float)b[0] + (float)a[1] * (float)b[1];
#endif
}

static inline int cdiv(int a, int b) { return (a + b - 1) / b; }

// basis from packed f16 fractions; bb[t] matches TAP[t]
__device__ __forceinline__ void unpack_bb(unsigned fr01, unsigned fr2u, float bb[8]) {
    h2 ab = __builtin_bit_cast(h2, fr01);
    h2 c2 = __builtin_bit_cast(h2, fr2u);
    float f0 = (float)ab[0], f1 = (float)ab[1], f2 = (float)c2[0];
    float a0 = 1.f - f0, a1 = 1.f - f1, a2 = 1.f - f2;
    float p00 = a0 * a1, p10 = f0 * a1, p01 = a0 * f1, p11 = f0 * f1;
    bb[0] = p00 * a2; bb[1] = p10 * a2; bb[2] = p01 * a2; bb[3] = p11 * a2;
    bb[4] = p00 * f2; bb[5] = p10 * f2; bb[6] = p01 * f2; bb[7] = p11 * f2;
}

__device__ __forceinline__ void spline_wf(const float* __restrict__ a3,
                                          int& wib, float fr[3]) {
    int k[3];
#pragma unroll
    for (int d = 0; d < 3; ++d) {
        float p = fminf(fmaxf(a3[d], 0.f), 1.f) * 4.f;
        float f0 = fminf(floorf(p), 3.f);
        k[d] = (int)f0;
        fr[d] = p - f0;
    }
    wib = k[0] * 25 + k[1] * 5 + k[2];
}

// ---------- preamble kernels ----------

__global__ void transform_kernel(const float* __restrict__ x,
                                 float* __restrict__ h, int n) {
    int i = blockIdx.x * blockDim.x + threadIdx.x;
    if (i < n) {
        float t = (x[i] - LOWER_CURV) / (UPPER_CURV - LOWER_CURV) * 20.0f - 10.0f;
        h[i] = fminf(fmaxf(t, -10.0f), 10.0f);
    }
}

__global__ void zero_int(int* __restrict__ p, int n) {
    int i = blockIdx.x * blockDim.x + threadIdx.x;
    if (i < n) p[i] = 0;
}

// dst histogram + wib histogram in one pass
__global__ void edge_hist(const int* __restrict__ dst, const float* __restrict__ attr,
                          int* __restrict__ counts, int* __restrict__ bcnt, int E) {
    int e = blockIdx.x * blockDim.x + threadIdx.x;
    if (e >= E) return;
    atomicAdd(&counts[dst[e]], 1);
    float a3[3] = {attr[e * 3], attr[e * 3 + 1], attr[e * 3 + 2]};
    int wib; float fr[3];
    spline_wf(a3, wib, fr);
    atomicAdd(&bcnt[wib], 1);
}

__global__ void scan_blocks(const int* __restrict__ counts, int* __restrict__ rowptr,
                            int* __restrict__ bsums, int n) {
    __shared__ int sh[256];
    int tid = threadIdx.x;
    int i = blockIdx.x * 256 + tid;
    int v = (i < n) ? counts[i] : 0;
    sh[tid] = v;
    __syncthreads();
    for (int off = 1; off < 256; off <<= 1) {
        int t = (tid >= off) ? sh[tid - off] : 0;
        __syncthreads();
        sh[tid] += t;
        __syncthreads();
    }
    if (i < n) rowptr[i] = sh[tid] - v;
    if (tid == 255) bsums[blockIdx.x] = sh[255];
}

__global__ void scan_sums(int* __restrict__ bsums, int nb) {
    __shared__ int sh[256];
    int tid = threadIdx.x;
    int v = (tid < nb) ? bsums[tid] : 0;
    sh[tid] = v;
    __syncthreads();
    for (int off = 1; off < 256; off <<= 1) {
        int t = (tid >= off) ? sh[tid - off] : 0;
        __syncthreads();
        sh[tid] += t;
        __syncthreads();
    }
    if (tid < nb) bsums[tid] = sh[tid] - v;
}

__global__ void add_offsets(int* __restrict__ rowptr, const int* __restrict__ bsums,
                            int* __restrict__ cursor, int n, int E) {
    int i = blockIdx.x * 256 + threadIdx.x;
    if (i < n) {
        int r = rowptr[i] + bsums[blockIdx.x];
        rowptr[i] = r;
        cursor[i] = r;
    }
    if (i == 0) rowptr[n] = E;
}

// 125-bucket exclusive scan with 8-alignment padding; bases[125] = Epad
__global__ void bucket_scan(const int* __restrict__ bcnt, int* __restrict__ bases,
                            int* __restrict__ bcursor) {
    __shared__ int sh[128];
    int tid = threadIdx.x;     // 128 threads
    int cap = (tid < KTOT) ? ((bcnt[tid] + 7) & ~7) : 0;
    sh[tid] = cap;
    __syncthreads();
    for (int off = 1; off < 128; off <<= 1) {
        int t = (tid >= off) ? sh[tid - off] : 0;
        __syncthreads();
        sh[tid] += t;
        __syncthreads();
    }
    int excl = sh[tid] - cap;
    if (tid < KTOT) {
        bases[tid] = excl;
        bcursor[tid] = excl;
        if (tid == KTOT - 1) bases[KTOT] = excl + cap;
    }
}

// scatter: records into wib-bucket order; perm maps dst-CSR position -> bucket pos
__global__ void edge_scatter(const int* __restrict__ src, const int* __restrict__ dst,
                             const float* __restrict__ attr, int* __restrict__ bcursor,
                             int* __restrict__ cursor, uint4* __restrict__ records,
                             int* __restrict__ perm, int E) {
    int e = blockIdx.x * blockDim.x + threadIdx.x;
    if (e >= E) return;
    float a3[3] = {attr[e * 3], attr[e * 3 + 1], attr[e * 3 + 2]};
    int wib; float fr[3];
    spline_wf(a3, wib, fr);
    unsigned fr01 = pack_u32(fr[0], fr[1]);
    unsigned fr2u = pack_u32(fr[2], 0.f);
    int pos = atomicAdd(&bcursor[wib], 1);
    records[pos] = make_uint4((unsigned)src[e], fr01, fr2u, (unsigned)wib);
    int p = atomicAdd(&cursor[dst[e]], 1);
    perm[p] = pos;
}

// fill bucket tail pads with harmless records (y rows never referenced by perm)
__global__ void pad_fill(const int* __restrict__ bcnt, const int* __restrict__ bases,
                         uint4* __restrict__ records) {
    int b = blockIdx.x;
    int s = bases[b] + bcnt[b];
    int epad = bases[b + 1];
    for (int i = s + threadIdx.x; i < epad; i += blockDim.x)
        records[i] = make_uint4(0u, 0u, 0u, (unsigned)b);
}

// f16 weight table: Wh[wi*(Cin*Cout) + (i>>3)*(8*Cout) + o*8 + (i&7)] = W[wi][i][o]
__global__ void prep_wh(const float* __restrict__ W, _Float16* __restrict__ Wh,
                        int Cin, int Cout) {
    int idx = blockIdx.x * blockDim.x + threadIdx.x;
    int tot = KTOT * Cin * Cout;
    if (idx >= tot) return;
    int wi = idx / (Cin * Cout);
    int r = idx % (Cin * Cout);
    int i = r / Cout, o = r % Cout;
    Wh[wi * (Cin * Cout) + (i >> 3) * (8 * Cout) + o * 8 + (i & 7)] = (_Float16)W[idx];
}

// ---------- phase A: bucket-ordered edge GEMM (same-wib broadcast LDS reads) ----------
template<int Cin, int Cout>
__global__ __launch_bounds__(512) void edge_gemm(
        const uint4* __restrict__ records, const float* __restrict__ x,
        const _Float16* __restrict__ Wg, const int* __restrict__ epad_ptr,
        _Float16* __restrict__ y) {
    constexpr int SLOTS = 64 / Cout;
    constexpr int WH = KTOT * Cin * Cout;
    __shared__ __align__(16) _Float16 Wl[WH];
    for (int t = threadIdx.x; t < WH / 8; t += 512)
        ((uint4*)Wl)[t] = ((const uint4*)Wg)[t];
    __syncthreads();

    const int Ep = *epad_ptr;
    const int lane = threadIdx.x & 63;
    const int o = lane & (Cout - 1);
    const int slot = lane / Cout;
    const int wid = blockIdx.x * 8 + (threadIdx.x >> 6);
    const int stride = gridDim.x * 8;
    constexpr int TAP[8] = {0, 25, 5, 30, 1, 26, 6, 31};

    for (int base = wid * SLOTS; base < Ep; base += stride * SLOTS) {
        uint4 rec = records[base + slot];          // same bucket across wave (8-aligned)
        float bb[8];
        unpack_bb(rec.y, rec.z, bb);
        const int wib = (int)rec.w;

        h2 hx[Cin / 2];
        const float4* xp = (const float4*)(x + (size_t)rec.x * Cin);
#pragma unroll
        for (int c = 0; c < Cin / 4; ++c) {
            float4 q = xp[c];
            hx[2 * c]     = pack_f16(q.x, q.y);
            hx[2 * c + 1] = pack_f16(q.z, q.w);
        }
        float acc = 0.f;
#pragma unroll
        for (int t = 0; t < 8; ++t) {
            const int wi = wib + TAP[t];
            const _Float16* wp = &Wl[wi * (Cin * Cout) + o * 8];
            float dot = 0.f;
#pragma unroll
            for (int c = 0; c < Cin / 8; ++c) {
                union { uint4 u4; unsigned u[4]; } wu;
                wu.u4 = *(const uint4*)(wp + c * (8 * Cout));
                dot = fdot2f(hx[4 * c + 0], __builtin_bit_cast(h2, wu.u[0]), dot);
                dot = fdot2f(hx[4 * c + 1], __builtin_bit_cast(h2, wu.u[1]), dot);
                dot = fdot2f(hx[4 * c + 2], __builtin_bit_cast(h2, wu.u[2]), dot);
                dot = fdot2f(hx[4 * c + 3], __builtin_bit_cast(h2, wu.u[3]), dot);
            }
            acc = fmaf(bb[t], dot, acc);
        }
        y[(size_t)base * Cout + lane] = (_Float16)acc;   // coalesced
    }
}

// ---------- phase B: per-(node, channel) gather-reduce + root + ELU ----------
template<int Cin, int Cout>
__global__ void node_reduce(const int* __restrict__ rowptr, const int* __restrict__ perm,
                            const _Float16* __restrict__ y, const float* __restrict__ x,
                            const float* __restrict__ root, const float* __restrict__ bias,
                            float* __restrict__ out, int N) {
    int t = blockIdx.x * blockDim.x + threadIdx.x;
    int v = t / Cout, o = t % Cout;
    if (v >= N) return;
    int beg = rowptr[v], end = rowptr[v + 1];
    float a0 = 0.f, a1 = 0.f;
    int p = beg;
    for (; p + 1 < end; p += 2) {
        int q0 = perm[p], q1 = perm[p + 1];
        a0 += (float)y[(size_t)q0 * Cout + o];
        a1 += (float)y[(size_t)q1 * Cout + o];
    }
    if (p < end) a0 += (float)y[(size_t)perm[p] * Cout + o];
    float acc = a0 + a1 + bias[o];
#pragma unroll
    for (int i = 0; i < Cin; ++i)
        acc = fmaf(x[(size_t)v * Cin + i], root[i * Cout + o], acc);
    out[(size_t)v * Cout + o] = acc > 0.f ? acc : expm1f(acc);
}

// ---------- fused small layers (dst-CSR, perm-gathered records) ----------

__global__ __launch_bounds__(512) void agg_l1(
        const int* __restrict__ rowptr, const int* __restrict__ perm,
        const uint4* __restrict__ records, const float* __restrict__ x,
        const float* __restrict__ W, const float* __restrict__ root,
        const float* __restrict__ bias, float* __restrict__ out,
        int N, int totalWaves) {
    const int lane = threadIdx.x & 63;
    const int o = lane & 7;
    const int slot = lane >> 3;
    const int wid = blockIdx.x * 8 + (threadIdx.x >> 6);
    constexpr int TAP[8] = {0, 25, 5, 30, 1, 26, 6, 31};

    for (int v = wid; v < N; v += totalWaves) {
        const int beg = rowptr[v], end = rowptr[v + 1];
        float acc = 0.0f;
        for (int p0 = beg; p0 < end; p0 += 8) {
            const int p = p0 + slot;
            float xv = 0.f, bb[8];
            int wib = 0;
#pragma unroll
            for (int t = 0; t < 8; ++t) bb[t] = 0.f;
            if (p < end) {
                uint4 rec = records[perm[p]];
                unpack_bb(rec.y, rec.z, bb);
                wib = (int)rec.w;
                xv = x[rec.x];
            }
#pragma unroll
            for (int t = 0; t < 8; ++t)
                acc = fmaf(bb[t] * xv, __ldg(&W[(wib + TAP[t]) * 8 + o]), acc);
        }
#pragma unroll
        for (int m = 8; m < 64; m <<= 1) acc += __shfl_xor(acc, m);
        if (slot == 0) {
            float z = acc + bias[o] + x[v] * root[o];
            out[(size_t)v * 8 + o] = z > 0.0f ? z : expm1f(z);
        }
    }
}

__global__ __launch_bounds__(512) void agg_l5(
        const int* __restrict__ rowptr, const int* __restrict__ perm,
        const uint4* __restrict__ records, const float* __restrict__ x,
        const float* __restrict__ W, const float* __restrict__ root,
        const float* __restrict__ bias, float* __restrict__ out,
        int N, int totalWaves) {
    const int lane = threadIdx.x & 63;
    const int i = lane & 7;
    const int slot = lane >> 3;
    const int wid = blockIdx.x * 8 + (threadIdx.x >> 6);
    constexpr int TAP[8] = {0, 25, 5, 30, 1, 26, 6, 31};

    for (int v = wid; v < N; v += totalWaves) {
        const int beg = rowptr[v], end = rowptr[v + 1];
        float acc = 0.0f;
        for (int p0 = beg; p0 < end; p0 += 8) {
            const int p = p0 + slot;
            float xi = 0.f, bb[8];
            int wib = 0;
#pragma unroll
            for (int t = 0; t < 8; ++t) bb[t] = 0.f;
            if (p < end) {
                uint4 rec = records[perm[p]];
                unpack_bb(rec.y, rec.z, bb);
                wib = (int)rec.w;
                xi = x[(size_t)rec.x * 8 + i];
            }
#pragma unroll
            for (int t = 0; t < 8; ++t)
                acc = fmaf(bb[t] * xi, __ldg(&W[(wib + TAP[t]) * 8 + i]), acc);
        }
        if (slot == 0) acc = fmaf(x[(size_t)v * 8 + i], root[i], acc);
#pragma unroll
        for (int m = 1; m < 64; m <<= 1) acc += __shfl_xor(acc, m);
        if (lane == 0) {
            float z = acc + bias[0];
            out[v] = z > 0.0f ? z : expm1f(z);
        }
    }
}

// ---------- host ----------

static inline char* align256(char* p) {
    return (char*)(((uintptr_t)p + 255) & ~(uintptr_t)255);
}

extern "C" void kernel_launch(void* const* d_in, const int* in_sizes, int n_in,
                              void* d_out, int out_size, void* d_ws, size_t ws_size,
                              hipStream_t stream) {
    const float* x    = (const float*)d_in[0];
    const int*   ei   = (const int*)d_in[1];
    const float* attr = (const float*)d_in[2];
    const float* w[5]    = {(const float*)d_in[3],  (const float*)d_in[6],
                            (const float*)d_in[9],  (const float*)d_in[12],
                            (const float*)d_in[15]};
    const float* root[5] = {(const float*)d_in[4],  (const float*)d_in[7],
                            (const float*)d_in[10], (const float*)d_in[13],
                            (const float*)d_in[16]};
    const float* bias[5] = {(const float*)d_in[5],  (const float*)d_in[8],
                            (const float*)d_in[11], (const float*)d_in[14],
                            (const float*)d_in[17]};

    const int N = in_sizes[0];
    const int E = in_sizes[1] / 2;
    const int* src = ei;
    const int* dst = ei + E;
    const int EP = E + 1024;     // capacity incl. bucket pads

    char* ws = (char*)d_ws;
    float* bufA    = (float*)ws;  ws = align256(ws + (size_t)N * 16 * 4);
    float* bufB    = (float*)ws;  ws = align256(ws + (size_t)N * 16 * 4);
    int*   counts  = (int*)ws;    ws = align256(ws + (size_t)(N + KTOT) * 4); // counts[N] + bcnt[125]
    int*   bcnt    = counts + N;
    int*   cursor  = (int*)ws;    ws = align256(ws + (size_t)N * 4);
    int*   rowptr  = (int*)ws;    ws = align256(ws + (size_t)(N + 1) * 4);
    int*   bsums   = (int*)ws;    ws = align256(ws + 256 * 4);
    int*   bases   = (int*)ws;    ws = align256(ws + (KTOT + 1) * 4);
    int*   bcursor = (int*)ws;    ws = align256(ws + KTOT * 4);
    uint4* records = (uint4*)ws;  ws = align256(ws + (size_t)EP * 16);
    int*   perm    = (int*)ws;    ws = align256(ws + (size_t)E * 4);
    _Float16* y    = (_Float16*)ws; ws = align256(ws + (size_t)EP * 16 * 2);
    _Float16* wh2  = (_Float16*)ws; ws = align256(ws + (size_t)KTOT * 8 * 16 * 2);
    _Float16* wh3  = (_Float16*)ws; ws = align256(ws + (size_t)KTOT * 16 * 16 * 2);
    _Float16* wh4  = (_Float16*)ws; ws = align256(ws + (size_t)KTOT * 16 * 8 * 2);

    const int B = 256;
    const int nb = cdiv(N, 256);

    transform_kernel<<<cdiv(N, B), B, 0, stream>>>(x, bufA, N);
    zero_int<<<cdiv(N + KTOT, B), B, 0, stream>>>(counts, N + KTOT);
    edge_hist<<<cdiv(E, B), B, 0, stream>>>(dst, attr, counts, bcnt, E);
    scan_blocks<<<nb, 256, 0, stream>>>(counts, rowptr, bsums, N);
    scan_sums<<<1, 256, 0, stream>>>(bsums, nb);
    add_offsets<<<nb, 256, 0, stream>>>(rowptr, bsums, cursor, N, E);
    bucket_scan<<<1, 128, 0, stream>>>(bcnt, bases, bcursor);
    edge_scatter<<<cdiv(E, B), B, 0, stream>>>(src, dst, attr, bcursor, cursor,
                                               records, perm, E);
    pad_fill<<<KTOT, 64, 0, stream>>>(bcnt, bases, records);

    prep_wh<<<cdiv(KTOT * 8 * 16, B), B, 0, stream>>>(w[1], wh2, 8, 16);
    prep_wh<<<cdiv(KTOT * 16 * 16, B), B, 0, stream>>>(w[2], wh3, 16, 16);
    prep_wh<<<cdiv(KTOT * 16 * 8, B), B, 0, stream>>>(w[3], wh4, 16, 8);

    const int GB = 512, TW = GB * 8;
    const int* epad = bases + KTOT;

    // L1 (1->8), fused
    agg_l1<<<GB, 512, 0, stream>>>(rowptr, perm, records, bufA, w[0],
                                   root[0], bias[0], bufB, N, TW);
    // L2 (8->16)
    edge_gemm<8, 16><<<1024, 512, 0, stream>>>(records, bufB, wh2, epad, y);
    node_reduce<8, 16><<<cdiv(N * 16, B), B, 0, stream>>>(rowptr, perm, y, bufB,
                                                          root[1], bias[1], bufA, N);
    // L3 (16->16)
    edge_gemm<16, 16><<<512, 512, 0, stream>>>(records, bufA, wh3, epad, y);
    node_reduce<16, 16><<<cdiv(N * 16, B), B, 0, stream>>>(rowptr, perm, y, bufA,
                                                           root[2], bias[2], bufB, N);
    // L4 (16->8)
    edge_gemm<16, 8><<<1024, 512, 0, stream>>>(records, bufB, wh4, epad, y);
    node_reduce<16, 8><<<cdiv(N * 8, B), B, 0, stream>>>(rowptr, perm, y, bufB,
                                                         root[3], bias[3], bufA, N);
    // L5 (8->1), fused
    agg_l5<<<GB, 512, 0, stream>>>(rowptr, perm, records, bufA, w[4],
                                   root[4], bias[4], (float*)d_out, N, TW);
}

// Round 6
// 250.975 us; speedup vs baseline: 4.2933x; 4.2933x over previous
//
#include <hip/hip_runtime.h>
#include <math.h>

#define KSIZE 5
#define KTOT 125
#define CHUNK 2048

static constexpr float LOWER_CURV = -0.22703196f;
static constexpr float UPPER_CURV = 0.36853024f;

typedef _Float16 h2 __attribute__((ext_vector_type(2)));

__device__ __forceinline__ h2 pack_f16(float a, float b) {
    return __builtin_bit_cast(h2, __builtin_amdgcn_cvt_pkrtz(a, b));
}
__device__ __forceinline__ unsigned pack_u32(float a, float b) {
    return __builtin_bit_cast(unsigned, __builtin_amdgcn_cvt_pkrtz(a, b));
}
__device__ __forceinline__ float fdot2f(h2 a, h2 b, float c) {
#if __has_builtin(__builtin_amdgcn_fdot2)
    return __builtin_amdgcn_fdot2(a, b, c, false);
#else
    return c + (float)a[0] * (float)b[0] + (float)a[1] * (float)b[1];
#endif
}

static inline int cdiv(int a, int b) { return (a + b - 1) / b; }

// basis from packed f16 fractions; bb[t] matches TAP[t]
__device__ __forceinline__ void unpack_bb(unsigned fr01, unsigned fr2u, float bb[8]) {
    h2 ab = __builtin_bit_cast(h2, fr01);
    h2 c2 = __builtin_bit_cast(h2, fr2u);
    float f0 = (float)ab[0], f1 = (float)ab[1], f2 = (float)c2[0];
    float a0 = 1.f - f0, a1 = 1.f - f1, a2 = 1.f - f2;
    float p00 = a0 * a1, p10 = f0 * a1, p01 = a0 * f1, p11 = f0 * f1;
    bb[0] = p00 * a2; bb[1] = p10 * a2; bb[2] = p01 * a2; bb[3] = p11 * a2;
    bb[4] = p00 * f2; bb[5] = p10 * f2; bb[6] = p01 * f2; bb[7] = p11 * f2;
}

__device__ __forceinline__ void spline_wf(const float* __restrict__ a3,
                                          int& wib, float fr[3]) {
    int k[3];
#pragma unroll
    for (int d = 0; d < 3; ++d) {
        float p = fminf(fmaxf(a3[d], 0.f), 1.f) * 4.f;
        float f0 = fminf(floorf(p), 3.f);
        k[d] = (int)f0;
        fr[d] = p - f0;
    }
    wib = k[0] * 25 + k[1] * 5 + k[2];
}

// ---------- preamble kernels ----------

__global__ void transform_kernel(const float* __restrict__ x,
                                 float* __restrict__ h, int n) {
    int i = blockIdx.x * blockDim.x + threadIdx.x;
    if (i < n) {
        float t = (x[i] - LOWER_CURV) / (UPPER_CURV - LOWER_CURV) * 20.0f - 10.0f;
        h[i] = fminf(fmaxf(t, -10.0f), 10.0f);
    }
}

__global__ void zero_int(int* __restrict__ p, int n) {
    int i = blockIdx.x * blockDim.x + threadIdx.x;
    if (i < n) p[i] = 0;
}

// dst histogram (50K addrs, fire-and-forget) + block-aggregated wib histogram
__global__ __launch_bounds__(256) void edge_hist(
        const int* __restrict__ dst, const float* __restrict__ attr,
        int* __restrict__ counts, int* __restrict__ bcnt, int E) {
    __shared__ int lh[KTOT];
    for (int i = threadIdx.x; i < KTOT; i += 256) lh[i] = 0;
    __syncthreads();
    const int base = blockIdx.x * CHUNK;
#pragma unroll
    for (int k = 0; k < 8; ++k) {
        int e = base + threadIdx.x + k * 256;
        if (e < E) {
            atomicAdd(&counts[dst[e]], 1);
            float a3[3] = {attr[e * 3], attr[e * 3 + 1], attr[e * 3 + 2]};
            int wib; float fr[3];
            spline_wf(a3, wib, fr);
            atomicAdd(&lh[wib], 1);
        }
    }
    __syncthreads();
    for (int i = threadIdx.x; i < KTOT; i += 256) {
        int c = lh[i];
        if (c) atomicAdd(&bcnt[i], c);
    }
}

__global__ void scan_blocks(const int* __restrict__ counts, int* __restrict__ rowptr,
                            int* __restrict__ bsums, int n) {
    __shared__ int sh[256];
    int tid = threadIdx.x;
    int i = blockIdx.x * 256 + tid;
    int v = (i < n) ? counts[i] : 0;
    sh[tid] = v;
    __syncthreads();
    for (int off = 1; off < 256; off <<= 1) {
        int t = (tid >= off) ? sh[tid - off] : 0;
        __syncthreads();
        sh[tid] += t;
        __syncthreads();
    }
    if (i < n) rowptr[i] = sh[tid] - v;
    if (tid == 255) bsums[blockIdx.x] = sh[255];
}

__global__ void scan_sums(int* __restrict__ bsums, int nb) {
    __shared__ int sh[256];
    int tid = threadIdx.x;
    int v = (tid < nb) ? bsums[tid] : 0;
    sh[tid] = v;
    __syncthreads();
    for (int off = 1; off < 256; off <<= 1) {
        int t = (tid >= off) ? sh[tid - off] : 0;
        __syncthreads();
        sh[tid] += t;
        __syncthreads();
    }
    if (tid < nb) bsums[tid] = sh[tid] - v;
}

__global__ void add_offsets(int* __restrict__ rowptr, const int* __restrict__ bsums,
                            int* __restrict__ cursor, int n, int E) {
    int i = blockIdx.x * 256 + threadIdx.x;
    if (i < n) {
        int r = rowptr[i] + bsums[blockIdx.x];
        rowptr[i] = r;
        cursor[i] = r;
    }
    if (i == 0) rowptr[n] = E;
}

// 125-bucket exclusive scan with 8-alignment padding; bases[125] = Epad
__global__ void bucket_scan(const int* __restrict__ bcnt, int* __restrict__ bases,
                            int* __restrict__ bcursor) {
    __shared__ int sh[128];
    int tid = threadIdx.x;     // 128 threads
    int cap = (tid < KTOT) ? ((bcnt[tid] + 7) & ~7) : 0;
    sh[tid] = cap;
    __syncthreads();
    for (int off = 1; off < 128; off <<= 1) {
        int t = (tid >= off) ? sh[tid - off] : 0;
        __syncthreads();
        sh[tid] += t;
        __syncthreads();
    }
    int excl = sh[tid] - cap;
    if (tid < KTOT) {
        bases[tid] = excl;
        bcursor[tid] = excl;
        if (tid == KTOT - 1) bases[KTOT] = excl + cap;
    }
}

// block-aggregated bucket scatter: LDS hist -> one global reserve per (block,bucket)
__global__ __launch_bounds__(256) void edge_scatter(
        const int* __restrict__ src, const int* __restrict__ dst,
        const float* __restrict__ attr, int* __restrict__ bcursor,
        int* __restrict__ cursor, uint4* __restrict__ records,
        int* __restrict__ perm, int E) {
    __shared__ int lh[KTOT], lbase[KTOT], lrank[KTOT];
    for (int i = threadIdx.x; i < KTOT; i += 256) { lh[i] = 0; lrank[i] = 0; }
    __syncthreads();
    const int base = blockIdx.x * CHUNK;

    int wibs[8]; unsigned f01[8], f2u[8];
#pragma unroll
    for (int k = 0; k < 8; ++k) {
        int e = base + threadIdx.x + k * 256;
        wibs[k] = -1;
        if (e < E) {
            float a3[3] = {attr[e * 3], attr[e * 3 + 1], attr[e * 3 + 2]};
            int wib; float fr[3];
            spline_wf(a3, wib, fr);
            wibs[k] = wib;
            f01[k] = pack_u32(fr[0], fr[1]);
            f2u[k] = pack_u32(fr[2], 0.f);
            atomicAdd(&lh[wib], 1);
        }
    }
    __syncthreads();
    for (int i = threadIdx.x; i < KTOT; i += 256) {
        int c = lh[i];
        lbase[i] = c ? atomicAdd(&bcursor[i], c) : 0;
    }
    __syncthreads();
#pragma unroll
    for (int k = 0; k < 8; ++k) {
        int e = base + threadIdx.x + k * 256;
        if (e < E) {
            int w = wibs[k];
            int pos = lbase[w] + atomicAdd(&lrank[w], 1);
            records[pos] = make_uint4((unsigned)src[e], f01[k], f2u[k], (unsigned)w);
            int p = atomicAdd(&cursor[dst[e]], 1);
            perm[p] = pos;
        }
    }
}

// fill bucket tail pads with harmless records (y rows never referenced by perm)
__global__ void pad_fill(const int* __restrict__ bcnt, const int* __restrict__ bases,
                         uint4* __restrict__ records) {
    int b = blockIdx.x;
    int s = bases[b] + bcnt[b];
    int epad = bases[b + 1];
    for (int i = s + threadIdx.x; i < epad; i += blockDim.x)
        records[i] = make_uint4(0u, 0u, 0u, (unsigned)b);
}

// f16 weight table: Wh[wi*(Cin*Cout) + (i>>3)*(8*Cout) + o*8 + (i&7)] = W[wi][i][o]
__global__ void prep_wh(const float* __restrict__ W, _Float16* __restrict__ Wh,
                        int Cin, int Cout) {
    int idx = blockIdx.x * blockDim.x + threadIdx.x;
    int tot = KTOT * Cin * Cout;
    if (idx >= tot) return;
    int wi = idx / (Cin * Cout);
    int r = idx % (Cin * Cout);
    int i = r / Cout, o = r % Cout;
    Wh[wi * (Cin * Cout) + (i >> 3) * (8 * Cout) + o * 8 + (i & 7)] = (_Float16)W[idx];
}

// ---------- phase A: bucket-ordered edge GEMM (same-wib broadcast LDS reads) ----------
template<int Cin, int Cout>
__global__ __launch_bounds__(512) void edge_gemm(
        const uint4* __restrict__ records, const float* __restrict__ x,
        const _Float16* __restrict__ Wg, const int* __restrict__ epad_ptr,
        _Float16* __restrict__ y) {
    constexpr int SLOTS = 64 / Cout;
    constexpr int WH = KTOT * Cin * Cout;
    __shared__ __align__(16) _Float16 Wl[WH];
    for (int t = threadIdx.x; t < WH / 8; t += 512)
        ((uint4*)Wl)[t] = ((const uint4*)Wg)[t];
    __syncthreads();

    const int Ep = *epad_ptr;
    const int lane = threadIdx.x & 63;
    const int o = lane & (Cout - 1);
    const int slot = lane / Cout;
    const int wid = blockIdx.x * 8 + (threadIdx.x >> 6);
    const int stride = gridDim.x * 8;
    constexpr int TAP[8] = {0, 25, 5, 30, 1, 26, 6, 31};

    for (int base = wid * SLOTS; base < Ep; base += stride * SLOTS) {
        uint4 rec = records[base + slot];          // same bucket across wave (8-aligned)
        float bb[8];
        unpack_bb(rec.y, rec.z, bb);
        const int wib = (int)rec.w;

        h2 hx[Cin / 2];
        const float4* xp = (const float4*)(x + (size_t)rec.x * Cin);
#pragma unroll
        for (int c = 0; c < Cin / 4; ++c) {
            float4 q = xp[c];
            hx[2 * c]     = pack_f16(q.x, q.y);
            hx[2 * c + 1] = pack_f16(q.z, q.w);
        }
        float acc = 0.f;
#pragma unroll
        for (int t = 0; t < 8; ++t) {
            const int wi = wib + TAP[t];
            const _Float16* wp = &Wl[wi * (Cin * Cout) + o * 8];
            float dot = 0.f;
#pragma unroll
            for (int c = 0; c < Cin / 8; ++c) {
                union { uint4 u4; unsigned u[4]; } wu;
                wu.u4 = *(const uint4*)(wp + c * (8 * Cout));
                dot = fdot2f(hx[4 * c + 0], __builtin_bit_cast(h2, wu.u[0]), dot);
                dot = fdot2f(hx[4 * c + 1], __builtin_bit_cast(h2, wu.u[1]), dot);
                dot = fdot2f(hx[4 * c + 2], __builtin_bit_cast(h2, wu.u[2]), dot);
                dot = fdot2f(hx[4 * c + 3], __builtin_bit_cast(h2, wu.u[3]), dot);
            }
            acc = fmaf(bb[t], dot, acc);
        }
        y[(size_t)base * Cout + lane] = (_Float16)acc;   // coalesced
    }
}

// ---------- phase B: per-(node, channel) gather-reduce + root + ELU ----------
template<int Cin, int Cout>
__global__ void node_reduce(const int* __restrict__ rowptr, const int* __restrict__ perm,
                            const _Float16* __restrict__ y, const float* __restrict__ x,
                            const float* __restrict__ root, const float* __restrict__ bias,
                            float* __restrict__ out, int N) {
    int t = blockIdx.x * blockDim.x + threadIdx.x;
    int v = t / Cout, o = t % Cout;
    if (v >= N) return;
    int beg = rowptr[v], end = rowptr[v + 1];
    float a0 = 0.f, a1 = 0.f;
    int p = beg;
    for (; p + 1 < end; p += 2) {
        int q0 = perm[p], q1 = perm[p + 1];
        a0 += (float)y[(size_t)q0 * Cout + o];
        a1 += (float)y[(size_t)q1 * Cout + o];
    }
    if (p < end) a0 += (float)y[(size_t)perm[p] * Cout + o];
    float acc = a0 + a1 + bias[o];
#pragma unroll
    for (int i = 0; i < Cin; ++i)
        acc = fmaf(x[(size_t)v * Cin + i], root[i * Cout + o], acc);
    out[(size_t)v * Cout + o] = acc > 0.f ? acc : expm1f(acc);
}

// ---------- fused small layers (dst-CSR, perm-gathered records) ----------

__global__ __launch_bounds__(512) void agg_l1(
        const int* __restrict__ rowptr, const int* __restrict__ perm,
        const uint4* __restrict__ records, const float* __restrict__ x,
        const float* __restrict__ W, const float* __restrict__ root,
        const float* __restrict__ bias, float* __restrict__ out,
        int N, int totalWaves) {
    const int lane = threadIdx.x & 63;
    const int o = lane & 7;
    const int slot = lane >> 3;
    const int wid = blockIdx.x * 8 + (threadIdx.x >> 6);
    constexpr int TAP[8] = {0, 25, 5, 30, 1, 26, 6, 31};

    for (int v = wid; v < N; v += totalWaves) {
        const int beg = rowptr[v], end = rowptr[v + 1];
        float acc = 0.0f;
        for (int p0 = beg; p0 < end; p0 += 8) {
            const int p = p0 + slot;
            float xv = 0.f, bb[8];
            int wib = 0;
#pragma unroll
            for (int t = 0; t < 8; ++t) bb[t] = 0.f;
            if (p < end) {
                uint4 rec = records[perm[p]];
                unpack_bb(rec.y, rec.z, bb);
                wib = (int)rec.w;
                xv = x[rec.x];
            }
#pragma unroll
            for (int t = 0; t < 8; ++t)
                acc = fmaf(bb[t] * xv, __ldg(&W[(wib + TAP[t]) * 8 + o]), acc);
        }
#pragma unroll
        for (int m = 8; m < 64; m <<= 1) acc += __shfl_xor(acc, m);
        if (slot == 0) {
            float z = acc + bias[o] + x[v] * root[o];
            out[(size_t)v * 8 + o] = z > 0.0f ? z : expm1f(z);
        }
    }
}

__global__ __launch_bounds__(512) void agg_l5(
        const int* __restrict__ rowptr, const int* __restrict__ perm,
        const uint4* __restrict__ records, const float* __restrict__ x,
        const float* __restrict__ W, const float* __restrict__ root,
        const float* __restrict__ bias, float* __restrict__ out,
        int N, int totalWaves) {
    const int lane = threadIdx.x & 63;
    const int i = lane & 7;
    const int slot = lane >> 3;
    const int wid = blockIdx.x * 8 + (threadIdx.x >> 6);
    constexpr int TAP[8] = {0, 25, 5, 30, 1, 26, 6, 31};

    for (int v = wid; v < N; v += totalWaves) {
        const int beg = rowptr[v], end = rowptr[v + 1];
        float acc = 0.0f;
        for (int p0 = beg; p0 < end; p0 += 8) {
            const int p = p0 + slot;
            float xi = 0.f, bb[8];
            int wib = 0;
#pragma unroll
            for (int t = 0; t < 8; ++t) bb[t] = 0.f;
            if (p < end) {
                uint4 rec = records[perm[p]];
                unpack_bb(rec.y, rec.z, bb);
                wib = (int)rec.w;
                xi = x[(size_t)rec.x * 8 + i];
            }
#pragma unroll
            for (int t = 0; t < 8; ++t)
                acc = fmaf(bb[t] * xi, __ldg(&W[(wib + TAP[t]) * 8 + i]), acc);
        }
        if (slot == 0) acc = fmaf(x[(size_t)v * 8 + i], root[i], acc);
#pragma unroll
        for (int m = 1; m < 64; m <<= 1) acc += __shfl_xor(acc, m);
        if (lane == 0) {
            float z = acc + bias[0];
            out[v] = z > 0.0f ? z : expm1f(z);
        }
    }
}

// ---------- host ----------

static inline char* align256(char* p) {
    return (char*)(((uintptr_t)p + 255) & ~(uintptr_t)255);
}

extern "C" void kernel_launch(void* const* d_in, const int* in_sizes, int n_in,
                              void* d_out, int out_size, void* d_ws, size_t ws_size,
                              hipStream_t stream) {
    const float* x    = (const float*)d_in[0];
    const int*   ei   = (const int*)d_in[1];
    const float* attr = (const float*)d_in[2];
    const float* w[5]    = {(const float*)d_in[3],  (const float*)d_in[6],
                            (const float*)d_in[9],  (const float*)d_in[12],
                            (const float*)d_in[15]};
    const float* root[5] = {(const float*)d_in[4],  (const float*)d_in[7],
                            (const float*)d_in[10], (const float*)d_in[13],
                            (const float*)d_in[16]};
    const float* bias[5] = {(const float*)d_in[5],  (const float*)d_in[8],
                            (const float*)d_in[11], (const float*)d_in[14],
                            (const float*)d_in[17]};

    const int N = in_sizes[0];
    const int E = in_sizes[1] / 2;
    const int* src = ei;
    const int* dst = ei + E;
    const int EP = E + 1024;     // capacity incl. bucket pads

    char* ws = (char*)d_ws;
    float* bufA    = (float*)ws;  ws = align256(ws + (size_t)N * 16 * 4);
    float* bufB    = (float*)ws;  ws = align256(ws + (size_t)N * 16 * 4);
    int*   counts  = (int*)ws;    ws = align256(ws + (size_t)(N + KTOT) * 4); // counts[N] + bcnt[125]
    int*   bcnt    = counts + N;
    int*   cursor  = (int*)ws;    ws = align256(ws + (size_t)N * 4);
    int*   rowptr  = (int*)ws;    ws = align256(ws + (size_t)(N + 1) * 4);
    int*   bsums   = (int*)ws;    ws = align256(ws + 256 * 4);
    int*   bases   = (int*)ws;    ws = align256(ws + (KTOT + 1) * 4);
    int*   bcursor = (int*)ws;    ws = align256(ws + KTOT * 4);
    uint4* records = (uint4*)ws;  ws = align256(ws + (size_t)EP * 16);
    int*   perm    = (int*)ws;    ws = align256(ws + (size_t)E * 4);
    _Float16* y    = (_Float16*)ws; ws = align256(ws + (size_t)EP * 16 * 2);
    _Float16* wh2  = (_Float16*)ws; ws = align256(ws + (size_t)KTOT * 8 * 16 * 2);
    _Float16* wh3  = (_Float16*)ws; ws = align256(ws + (size_t)KTOT * 16 * 16 * 2);
    _Float16* wh4  = (_Float16*)ws; ws = align256(ws + (size_t)KTOT * 16 * 8 * 2);

    const int B = 256;
    const int nb = cdiv(N, 256);
    const int nchunk = cdiv(E, CHUNK);

    transform_kernel<<<cdiv(N, B), B, 0, stream>>>(x, bufA, N);
    zero_int<<<cdiv(N + KTOT, B), B, 0, stream>>>(counts, N + KTOT);
    edge_hist<<<nchunk, 256, 0, stream>>>(dst, attr, counts, bcnt, E);
    scan_blocks<<<nb, 256, 0, stream>>>(counts, rowptr, bsums, N);
    scan_sums<<<1, 256, 0, stream>>>(bsums, nb);
    add_offsets<<<nb, 256, 0, stream>>>(rowptr, bsums, cursor, N, E);
    bucket_scan<<<1, 128, 0, stream>>>(bcnt, bases, bcursor);
    edge_scatter<<<nchunk, 256, 0, stream>>>(src, dst, attr, bcursor, cursor,
                                             records, perm, E);
    pad_fill<<<KTOT, 64, 0, stream>>>(bcnt, bases, records);

    prep_wh<<<cdiv(KTOT * 8 * 16, B), B, 0, stream>>>(w[1], wh2, 8, 16);
    prep_wh<<<cdiv(KTOT * 16 * 16, B), B, 0, stream>>>(w[2], wh3, 16, 16);
    prep_wh<<<cdiv(KTOT * 16 * 8, B), B, 0, stream>>>(w[3], wh4, 16, 8);

    const int GB = 512, TW = GB * 8;
    const int* epad = bases + KTOT;

    // L1 (1->8), fused
    agg_l1<<<GB, 512, 0, stream>>>(rowptr, perm, records, bufA, w[0],
                                   root[0], bias[0], bufB, N, TW);
    // L2 (8->16)
    edge_gemm<8, 16><<<1024, 512, 0, stream>>>(records, bufB, wh2, epad, y);
    node_reduce<8, 16><<<cdiv(N * 16, B), B, 0, stream>>>(rowptr, perm, y, bufB,
                                                          root[1], bias[1], bufA, N);
    // L3 (16->16)
    edge_gemm<16, 16><<<512, 512, 0, stream>>>(records, bufA, wh3, epad, y);
    node_reduce<16, 16><<<cdiv(N * 16, B), B, 0, stream>>>(rowptr, perm, y, bufA,
                                                           root[2], bias[2], bufB, N);
    // L4 (16->8)
    edge_gemm<16, 8><<<1024, 512, 0, stream>>>(records, bufB, wh4, epad, y);
    node_reduce<16, 8><<<cdiv(N * 8, B), B, 0, stream>>>(rowptr, perm, y, bufB,
                                                         root[3], bias[3], bufA, N);
    // L5 (8->1), fused
    agg_l5<<<GB, 512, 0, stream>>>(rowptr, perm, records, bufA, w[4],
                                   root[4], bias[4], (float*)d_out, N, TW);
}

// Round 7
// 239.029 us; speedup vs baseline: 4.5078x; 1.0500x over previous
//
#include <hip/hip_runtime.h>
#include <math.h>

#define KSIZE 5
#define KTOT 125
#define CHUNK 2048

static constexpr float LOWER_CURV = -0.22703196f;
static constexpr float UPPER_CURV = 0.36853024f;

typedef _Float16 h2 __attribute__((ext_vector_type(2)));

__device__ __forceinline__ h2 pack_f16(float a, float b) {
    return __builtin_bit_cast(h2, __builtin_amdgcn_cvt_pkrtz(a, b));
}
__device__ __forceinline__ unsigned pack_u32(float a, float b) {
    return __builtin_bit_cast(unsigned, __builtin_amdgcn_cvt_pkrtz(a, b));
}
__device__ __forceinline__ float fdot2f(h2 a, h2 b, float c) {
#if __has_builtin(__builtin_amdgcn_fdot2)
    return __builtin_amdgcn_fdot2(a, b, c, false);
#else
    return c + (float)a[0] * (float)b[0] + (float)a[1] * (float)b[1];
#endif
}

static inline int cdiv(int a, int b) { return (a + b - 1) / b; }

// basis from packed f16 fractions; bb[t] matches TAP[t]
__device__ __forceinline__ void unpack_bb(unsigned fr01, unsigned fr2u, float bb[8]) {
    h2 ab = __builtin_bit_cast(h2, fr01);
    h2 c2 = __builtin_bit_cast(h2, fr2u);
    float f0 = (float)ab[0], f1 = (float)ab[1], f2 = (float)c2[0];
    float a0 = 1.f - f0, a1 = 1.f - f1, a2 = 1.f - f2;
    float p00 = a0 * a1, p10 = f0 * a1, p01 = a0 * f1, p11 = f0 * f1;
    bb[0] = p00 * a2; bb[1] = p10 * a2; bb[2] = p01 * a2; bb[3] = p11 * a2;
    bb[4] = p00 * f2; bb[5] = p10 * f2; bb[6] = p01 * f2; bb[7] = p11 * f2;
}

__device__ __forceinline__ void spline_wf(const float* __restrict__ a3,
                                          int& wib, float fr[3]) {
    int k[3];
#pragma unroll
    for (int d = 0; d < 3; ++d) {
        float p = fminf(fmaxf(a3[d], 0.f), 1.f) * 4.f;
        float f0 = fminf(floorf(p), 3.f);
        k[d] = (int)f0;
        fr[d] = p - f0;
    }
    wib = k[0] * 25 + k[1] * 5 + k[2];
}

// ---------- preamble kernels ----------

// transform x + zero the dst-histogram
__global__ void init_kernel(const float* __restrict__ x, float* __restrict__ h,
                            int* __restrict__ counts, int n) {
    int i = blockIdx.x * blockDim.x + threadIdx.x;
    if (i < n) {
        float t = (x[i] - LOWER_CURV) / (UPPER_CURV - LOWER_CURV) * 20.0f - 10.0f;
        h[i] = fminf(fmaxf(t, -10.0f), 10.0f);
        counts[i] = 0;
    }
}

__global__ void hist_dst(const int* __restrict__ dst, int* __restrict__ counts, int E) {
    int e = blockIdx.x * blockDim.x + threadIdx.x;
    if (e < E) atomicAdd(&counts[dst[e]], 1);
}

__global__ void scan_blocks(const int* __restrict__ counts, int* __restrict__ rowptr,
                            int* __restrict__ bsums, int n) {
    __shared__ int sh[256];
    int tid = threadIdx.x;
    int i = blockIdx.x * 256 + tid;
    int v = (i < n) ? counts[i] : 0;
    sh[tid] = v;
    __syncthreads();
    for (int off = 1; off < 256; off <<= 1) {
        int t = (tid >= off) ? sh[tid - off] : 0;
        __syncthreads();
        sh[tid] += t;
        __syncthreads();
    }
    if (i < n) rowptr[i] = sh[tid] - v;
    if (tid == 255) bsums[blockIdx.x] = sh[255];
}

__global__ void scan_sums(int* __restrict__ bsums, int nb) {
    __shared__ int sh[256];
    int tid = threadIdx.x;
    int v = (tid < nb) ? bsums[tid] : 0;
    sh[tid] = v;
    __syncthreads();
    for (int off = 1; off < 256; off <<= 1) {
        int t = (tid >= off) ? sh[tid - off] : 0;
        __syncthreads();
        sh[tid] += t;
        __syncthreads();
    }
    if (tid < nb) bsums[tid] = sh[tid] - v;
}

__global__ void add_offsets(int* __restrict__ rowptr, const int* __restrict__ bsums,
                            int* __restrict__ cursor, int n, int E) {
    int i = blockIdx.x * 256 + threadIdx.x;
    if (i < n) {
        int r = rowptr[i] + bsums[blockIdx.x];
        rowptr[i] = r;
        cursor[i] = r;
    }
    if (i == 0) rowptr[n] = E;
}

// chunk-local counting sort by wib: records land at blockIdx*CHUNK + localRank.
// No global bucket coordination; wib-runs of ~16 preserve LDS broadcast downstream.
__global__ __launch_bounds__(256) void edge_scatter(
        const int* __restrict__ src, const int* __restrict__ dst,
        const float* __restrict__ attr, int* __restrict__ cursor,
        uint4* __restrict__ records, int* __restrict__ perm, int E) {
    __shared__ int lh[KTOT], lbase[KTOT], lrank[KTOT];
    __shared__ int sb[128];
    for (int i = threadIdx.x; i < KTOT; i += 256) { lh[i] = 0; lrank[i] = 0; }
    __syncthreads();
    const int base = blockIdx.x * CHUNK;
    const int tid = threadIdx.x;

    int wibs[8]; unsigned f01[8], f2u[8];
#pragma unroll
    for (int k = 0; k < 8; ++k) {
        int e = base + tid + k * 256;
        wibs[k] = -1;
        if (e < E) {
            float a3[3] = {attr[e * 3], attr[e * 3 + 1], attr[e * 3 + 2]};
            int wib; float fr[3];
            spline_wf(a3, wib, fr);
            wibs[k] = wib;
            f01[k] = pack_u32(fr[0], fr[1]);
            f2u[k] = pack_u32(fr[2], 0.f);
            atomicAdd(&lh[wib], 1);
        }
    }
    __syncthreads();
    // exclusive scan of the 125 bin counts (Hillis-Steele on 128 lanes)
    int v0 = 0;
    if (tid < 128) {
        v0 = (tid < KTOT) ? lh[tid] : 0;
        sb[tid] = v0;
    }
    __syncthreads();
    for (int off = 1; off < 128; off <<= 1) {
        int t = (tid >= off && tid < 128) ? sb[tid - off] : 0;
        __syncthreads();
        if (tid < 128) sb[tid] += t;
        __syncthreads();
    }
    if (tid < KTOT) lbase[tid] = sb[tid] - v0;
    __syncthreads();
#pragma unroll
    for (int k = 0; k < 8; ++k) {
        int e = base + tid + k * 256;
        if (e < E) {
            int w = wibs[k];
            int pos = base + lbase[w] + atomicAdd(&lrank[w], 1);
            records[pos] = make_uint4((unsigned)src[e], f01[k], f2u[k], (unsigned)w);
            int p = atomicAdd(&cursor[dst[e]], 1);
            perm[p] = pos;
        }
    }
}

// all three f16 weight tables in one launch:
// Wh[wi*(Cin*Cout) + (i>>3)*(8*Cout) + o*8 + (i&7)] = W[wi][i][o]
__global__ void prep_all(const float* __restrict__ W2, const float* __restrict__ W3,
                         const float* __restrict__ W4, _Float16* __restrict__ wh2,
                         _Float16* __restrict__ wh3, _Float16* __restrict__ wh4) {
    int idx = blockIdx.x * blockDim.x + threadIdx.x;   // < 64000
    const float* W; _Float16* Wh; int Cin, Cout, r;
    if (idx < 16000)      { W = W2; Wh = wh2; Cin = 8;  Cout = 16; r = idx; }
    else if (idx < 48000) { W = W3; Wh = wh3; Cin = 16; Cout = 16; r = idx - 16000; }
    else if (idx < 64000) { W = W4; Wh = wh4; Cin = 16; Cout = 8;  r = idx - 48000; }
    else return;
    int wi = r / (Cin * Cout);
    int q = r % (Cin * Cout);
    int i = q / Cout, o = q % Cout;
    Wh[wi * (Cin * Cout) + (i >> 3) * (8 * Cout) + o * 8 + (i & 7)] = (_Float16)W[r];
}

// ---------- phase A: edge GEMM over chunk-sorted records ----------
template<int Cin, int Cout>
__global__ __launch_bounds__(512) void edge_gemm(
        const uint4* __restrict__ records, const float* __restrict__ x,
        const _Float16* __restrict__ Wg, _Float16* __restrict__ y, int E) {
    constexpr int SLOTS = 64 / Cout;
    constexpr int WH = KTOT * Cin * Cout;
    __shared__ __align__(16) _Float16 Wl[WH];
    for (int t = threadIdx.x; t < WH / 8; t += 512)
        ((uint4*)Wl)[t] = ((const uint4*)Wg)[t];
    __syncthreads();

    const int lane = threadIdx.x & 63;
    const int o = lane & (Cout - 1);
    const int slot = lane / Cout;
    const int wid = blockIdx.x * 8 + (threadIdx.x >> 6);
    const int stride = gridDim.x * 8;
    constexpr int TAP[8] = {0, 25, 5, 30, 1, 26, 6, 31};

    for (int base = wid * SLOTS; base < E; base += stride * SLOTS) {
        const int idx = base + slot;
        const bool act = idx < E;
        uint4 rec = act ? records[idx] : make_uint4(0u, 0u, 0u, 0u);
        float bb[8];
        unpack_bb(rec.y, rec.z, bb);
        const int wib = (int)rec.w;

        h2 hx[Cin / 2];
        const float4* xp = (const float4*)(x + (size_t)rec.x * Cin);
#pragma unroll
        for (int c = 0; c < Cin / 4; ++c) {
            float4 q = xp[c];
            hx[2 * c]     = pack_f16(q.x, q.y);
            hx[2 * c + 1] = pack_f16(q.z, q.w);
        }
        float acc = 0.f;
#pragma unroll
        for (int t = 0; t < 8; ++t) {
            const int wi = wib + TAP[t];
            const _Float16* wp = &Wl[wi * (Cin * Cout) + o * 8];
            float dot = 0.f;
#pragma unroll
            for (int c = 0; c < Cin / 8; ++c) {
                union { uint4 u4; unsigned u[4]; } wu;
                wu.u4 = *(const uint4*)(wp + c * (8 * Cout));
                dot = fdot2f(hx[4 * c + 0], __builtin_bit_cast(h2, wu.u[0]), dot);
                dot = fdot2f(hx[4 * c + 1], __builtin_bit_cast(h2, wu.u[1]), dot);
                dot = fdot2f(hx[4 * c + 2], __builtin_bit_cast(h2, wu.u[2]), dot);
                dot = fdot2f(hx[4 * c + 3], __builtin_bit_cast(h2, wu.u[3]), dot);
            }
            acc = fmaf(bb[t], dot, acc);
        }
        if (act) y[(size_t)idx * Cout + o + (slot ? 0 : 0) * 0] = (_Float16)acc;
    }
}

// ---------- phase B: per-(node, channel) gather-reduce + root + ELU ----------
template<int Cin, int Cout>
__global__ void node_reduce(const int* __restrict__ rowptr, const int* __restrict__ perm,
                            const _Float16* __restrict__ y, const float* __restrict__ x,
                            const float* __restrict__ root, const float* __restrict__ bias,
                            float* __restrict__ out, int N) {
    int t = blockIdx.x * blockDim.x + threadIdx.x;
    int v = t / Cout, o = t % Cout;
    if (v >= N) return;
    int beg = rowptr[v], end = rowptr[v + 1];
    float a0 = 0.f, a1 = 0.f;
    int p = beg;
    for (; p + 1 < end; p += 2) {
        int q0 = perm[p], q1 = perm[p + 1];
        a0 += (float)y[(size_t)q0 * Cout + o];
        a1 += (float)y[(size_t)q1 * Cout + o];
    }
    if (p < end) a0 += (float)y[(size_t)perm[p] * Cout + o];
    float acc = a0 + a1 + bias[o];
#pragma unroll
    for (int i = 0; i < Cin; ++i)
        acc = fmaf(x[(size_t)v * Cin + i], root[i * Cout + o], acc);
    out[(size_t)v * Cout + o] = acc > 0.f ? acc : expm1f(acc);
}

// ---------- fused small layers (dst-CSR, perm-gathered records) ----------

__global__ __launch_bounds__(512) void agg_l1(
        const int* __restrict__ rowptr, const int* __restrict__ perm,
        const uint4* __restrict__ records, const float* __restrict__ x,
        const float* __restrict__ W, const float* __restrict__ root,
        const float* __restrict__ bias, float* __restrict__ out,
        int N, int totalWaves) {
    const int lane = threadIdx.x & 63;
    const int o = lane & 7;
    const int slot = lane >> 3;
    const int wid = blockIdx.x * 8 + (threadIdx.x >> 6);
    constexpr int TAP[8] = {0, 25, 5, 30, 1, 26, 6, 31};

    for (int v = wid; v < N; v += totalWaves) {
        const int beg = rowptr[v], end = rowptr[v + 1];
        float acc = 0.0f;
        for (int p0 = beg; p0 < end; p0 += 8) {
            const int p = p0 + slot;
            float xv = 0.f, bb[8];
            int wib = 0;
#pragma unroll
            for (int t = 0; t < 8; ++t) bb[t] = 0.f;
            if (p < end) {
                uint4 rec = records[perm[p]];
                unpack_bb(rec.y, rec.z, bb);
                wib = (int)rec.w;
                xv = x[rec.x];
            }
#pragma unroll
            for (int t = 0; t < 8; ++t)
                acc = fmaf(bb[t] * xv, __ldg(&W[(wib + TAP[t]) * 8 + o]), acc);
        }
#pragma unroll
        for (int m = 8; m < 64; m <<= 1) acc += __shfl_xor(acc, m);
        if (slot == 0) {
            float z = acc + bias[o] + x[v] * root[o];
            out[(size_t)v * 8 + o] = z > 0.0f ? z : expm1f(z);
        }
    }
}

__global__ __launch_bounds__(512) void agg_l5(
        const int* __restrict__ rowptr, const int* __restrict__ perm,
        const uint4* __restrict__ records, const float* __restrict__ x,
        const float* __restrict__ W, const float* __restrict__ root,
        const float* __restrict__ bias, float* __restrict__ out,
        int N, int totalWaves) {
    const int lane = threadIdx.x & 63;
    const int i = lane & 7;
    const int slot = lane >> 3;
    const int wid = blockIdx.x * 8 + (threadIdx.x >> 6);
    constexpr int TAP[8] = {0, 25, 5, 30, 1, 26, 6, 31};

    for (int v = wid; v < N; v += totalWaves) {
        const int beg = rowptr[v], end = rowptr[v + 1];
        float acc = 0.0f;
        for (int p0 = beg; p0 < end; p0 += 8) {
            const int p = p0 + slot;
            float xi = 0.f, bb[8];
            int wib = 0;
#pragma unroll
            for (int t = 0; t < 8; ++t) bb[t] = 0.f;
            if (p < end) {
                uint4 rec = records[perm[p]];
                unpack_bb(rec.y, rec.z, bb);
                wib = (int)rec.w;
                xi = x[(size_t)rec.x * 8 + i];
            }
#pragma unroll
            for (int t = 0; t < 8; ++t)
                acc = fmaf(bb[t] * xi, __ldg(&W[(wib + TAP[t]) * 8 + i]), acc);
        }
        if (slot == 0) acc = fmaf(x[(size_t)v * 8 + i], root[i], acc);
#pragma unroll
        for (int m = 1; m < 64; m <<= 1) acc += __shfl_xor(acc, m);
        if (lane == 0) {
            float z = acc + bias[0];
            out[v] = z > 0.0f ? z : expm1f(z);
        }
    }
}

// ---------- host ----------

static inline char* align256(char* p) {
    return (char*)(((uintptr_t)p + 255) & ~(uintptr_t)255);
}

extern "C" void kernel_launch(void* const* d_in, const int* in_sizes, int n_in,
                              void* d_out, int out_size, void* d_ws, size_t ws_size,
                              hipStream_t stream) {
    const float* x    = (const float*)d_in[0];
    const int*   ei   = (const int*)d_in[1];
    const float* attr = (const float*)d_in[2];
    const float* w[5]    = {(const float*)d_in[3],  (const float*)d_in[6],
                            (const float*)d_in[9],  (const float*)d_in[12],
                            (const float*)d_in[15]};
    const float* root[5] = {(const float*)d_in[4],  (const float*)d_in[7],
                            (const float*)d_in[10], (const float*)d_in[13],
                            (const float*)d_in[16]};
    const float* bias[5] = {(const float*)d_in[5],  (const float*)d_in[8],
                            (const float*)d_in[11], (const float*)d_in[14],
                            (const float*)d_in[17]};

    const int N = in_sizes[0];
    const int E = in_sizes[1] / 2;
    const int* src = ei;
    const int* dst = ei + E;

    char* ws = (char*)d_ws;
    float* bufA    = (float*)ws;  ws = align256(ws + (size_t)N * 16 * 4);
    float* bufB    = (float*)ws;  ws = align256(ws + (size_t)N * 16 * 4);
    int*   counts  = (int*)ws;    ws = align256(ws + (size_t)N * 4);
    int*   cursor  = (int*)ws;    ws = align256(ws + (size_t)N * 4);
    int*   rowptr  = (int*)ws;    ws = align256(ws + (size_t)(N + 1) * 4);
    int*   bsums   = (int*)ws;    ws = align256(ws + 256 * 4);
    uint4* records = (uint4*)ws;  ws = align256(ws + (size_t)E * 16);
    int*   perm    = (int*)ws;    ws = align256(ws + (size_t)E * 4);
    _Float16* y    = (_Float16*)ws; ws = align256(ws + (size_t)E * 16 * 2);
    _Float16* wh2  = (_Float16*)ws; ws = align256(ws + (size_t)KTOT * 8 * 16 * 2);
    _Float16* wh3  = (_Float16*)ws; ws = align256(ws + (size_t)KTOT * 16 * 16 * 2);
    _Float16* wh4  = (_Float16*)ws; ws = align256(ws + (size_t)KTOT * 16 * 8 * 2);

    const int B = 256;
    const int nb = cdiv(N, 256);

    init_kernel<<<cdiv(N, B), B, 0, stream>>>(x, bufA, counts, N);
    hist_dst<<<cdiv(E, B), B, 0, stream>>>(dst, counts, E);
    scan_blocks<<<nb, 256, 0, stream>>>(counts, rowptr, bsums, N);
    scan_sums<<<1, 256, 0, stream>>>(bsums, nb);
    add_offsets<<<nb, 256, 0, stream>>>(rowptr, bsums, cursor, N, E);
    edge_scatter<<<cdiv(E, CHUNK), 256, 0, stream>>>(src, dst, attr, cursor,
                                                     records, perm, E);
    prep_all<<<cdiv(64000, B), B, 0, stream>>>(w[1], w[2], w[3], wh2, wh3, wh4);

    const int GB = 512, TW = GB * 8;

    // L1 (1->8), fused
    agg_l1<<<GB, 512, 0, stream>>>(rowptr, perm, records, bufA, w[0],
                                   root[0], bias[0], bufB, N, TW);
    // L2 (8->16)
    edge_gemm<8, 16><<<1024, 512, 0, stream>>>(records, bufB, wh2, y, E);
    node_reduce<8, 16><<<cdiv(N * 16, B), B, 0, stream>>>(rowptr, perm, y, bufB,
                                                          root[1], bias[1], bufA, N);
    // L3 (16->16)
    edge_gemm<16, 16><<<512, 512, 0, stream>>>(records, bufA, wh3, y, E);
    node_reduce<16, 16><<<cdiv(N * 16, B), B, 0, stream>>>(rowptr, perm, y, bufA,
                                                           root[2], bias[2], bufB, N);
    // L4 (16->8)
    edge_gemm<16, 8><<<1024, 512, 0, stream>>>(records, bufB, wh4, y, E);
    node_reduce<16, 8><<<cdiv(N * 8, B), B, 0, stream>>>(rowptr, perm, y, bufB,
                                                         root[3], bias[3], bufA, N);
    // L5 (8->1), fused
    agg_l5<<<GB, 512, 0, stream>>>(rowptr, perm, records, bufA, w[4],
                                   root[4], bias[4], (float*)d_out, N, TW);
}

// Round 8
// 209.037 us; speedup vs baseline: 5.1546x; 1.1435x over previous
//
#include <hip/hip_runtime.h>
#include <math.h>

#define KSIZE 5
#define KTOT 125
#define CHUNK 2048

static constexpr float LOWER_CURV = -0.22703196f;
static constexpr float UPPER_CURV = 0.36853024f;

typedef _Float16 h2 __attribute__((ext_vector_type(2)));

__device__ __forceinline__ h2 pack_f16(float a, float b) {
    return __builtin_bit_cast(h2, __builtin_amdgcn_cvt_pkrtz(a, b));
}
__device__ __forceinline__ unsigned pack_u32(float a, float b) {
    return __builtin_bit_cast(unsigned, __builtin_amdgcn_cvt_pkrtz(a, b));
}
__device__ __forceinline__ float fdot2f(h2 a, h2 b, float c) {
#if __has_builtin(__builtin_amdgcn_fdot2)
    return __builtin_amdgcn_fdot2(a, b, c, false);
#else
    return c + (float)a[0] * (float)b[0] + (float)a[1] * (float)b[1];
#endif
}

static inline int cdiv(int a, int b) { return (a + b - 1) / b; }

// basis from packed f16 fractions; bb[t] matches TAP[t]
__device__ __forceinline__ void unpack_bb(unsigned fr01, unsigned fr2u, float bb[8]) {
    h2 ab = __builtin_bit_cast(h2, fr01);
    h2 c2 = __builtin_bit_cast(h2, fr2u);
    float f0 = (float)ab[0], f1 = (float)ab[1], f2 = (float)c2[0];
    float a0 = 1.f - f0, a1 = 1.f - f1, a2 = 1.f - f2;
    float p00 = a0 * a1, p10 = f0 * a1, p01 = a0 * f1, p11 = f0 * f1;
    bb[0] = p00 * a2; bb[1] = p10 * a2; bb[2] = p01 * a2; bb[3] = p11 * a2;
    bb[4] = p00 * f2; bb[5] = p10 * f2; bb[6] = p01 * f2; bb[7] = p11 * f2;
}

__device__ __forceinline__ void spline_wf(const float* __restrict__ a3,
                                          int& wib, float fr[3]) {
    int k[3];
#pragma unroll
    for (int d = 0; d < 3; ++d) {
        float p = fminf(fmaxf(a3[d], 0.f), 1.f) * 4.f;
        float f0 = fminf(floorf(p), 3.f);
        k[d] = (int)f0;
        fr[d] = p - f0;
    }
    wib = k[0] * 25 + k[1] * 5 + k[2];
}

// ---------- preamble kernels ----------

__global__ void init_kernel(const float* __restrict__ x, float* __restrict__ h,
                            int* __restrict__ counts, int n) {
    int i = blockIdx.x * blockDim.x + threadIdx.x;
    if (i < n) {
        float t = (x[i] - LOWER_CURV) / (UPPER_CURV - LOWER_CURV) * 20.0f - 10.0f;
        h[i] = fminf(fmaxf(t, -10.0f), 10.0f);
        counts[i] = 0;
    }
}

__global__ void hist_dst(const int* __restrict__ dst, int* __restrict__ counts, int E) {
    int e = blockIdx.x * blockDim.x + threadIdx.x;
    if (e < E) atomicAdd(&counts[dst[e]], 1);
}

__global__ void scan_blocks(const int* __restrict__ counts, int* __restrict__ rowptr,
                            int* __restrict__ bsums, int n) {
    __shared__ int sh[256];
    int tid = threadIdx.x;
    int i = blockIdx.x * 256 + tid;
    int v = (i < n) ? counts[i] : 0;
    sh[tid] = v;
    __syncthreads();
    for (int off = 1; off < 256; off <<= 1) {
        int t = (tid >= off) ? sh[tid - off] : 0;
        __syncthreads();
        sh[tid] += t;
        __syncthreads();
    }
    if (i < n) rowptr[i] = sh[tid] - v;
    if (tid == 255) bsums[blockIdx.x] = sh[255];
}

// per-block redundant scan of bsums, then offset rowptr & init cursor (1 launch)
__global__ void add_offsets2(int* __restrict__ rowptr, const int* __restrict__ bsums,
                             int* __restrict__ cursor, int nb, int n, int E) {
    __shared__ int sh[256];
    int tid = threadIdx.x;
    int v = (tid < nb) ? bsums[tid] : 0;
    sh[tid] = v;
    __syncthreads();
    for (int off = 1; off < 256; off <<= 1) {
        int t = (tid >= off) ? sh[tid - off] : 0;
        __syncthreads();
        sh[tid] += t;
        __syncthreads();
    }
    int boff = (blockIdx.x == 0) ? 0 : sh[blockIdx.x - 1];
    int i = blockIdx.x * 256 + tid;
    if (i < n) {
        int r = rowptr[i] + boff;
        rowptr[i] = r;
        cursor[i] = r;
    }
    if (i == 0) rowptr[n] = E;
}

// chunk-local counting sort by wib; dual output:
//   records   (bucket order, for edge_gemm)
//   records_d (dst-CSR order, for l1/l5)  + iperm (bucket pos -> dst pos)
__global__ __launch_bounds__(256) void edge_scatter(
        const int* __restrict__ src, const int* __restrict__ dst,
        const float* __restrict__ attr, int* __restrict__ cursor,
        uint4* __restrict__ records, uint4* __restrict__ records_d,
        int* __restrict__ iperm, int E) {
    __shared__ int lh[KTOT], lbase[KTOT], lrank[KTOT];
    __shared__ int sb[128];
    for (int i = threadIdx.x; i < KTOT; i += 256) { lh[i] = 0; lrank[i] = 0; }
    __syncthreads();
    const int base = blockIdx.x * CHUNK;
    const int tid = threadIdx.x;

    int wibs[8]; unsigned f01[8], f2u[8];
#pragma unroll
    for (int k = 0; k < 8; ++k) {
        int e = base + tid + k * 256;
        wibs[k] = -1;
        if (e < E) {
            float a3[3] = {attr[e * 3], attr[e * 3 + 1], attr[e * 3 + 2]};
            int wib; float fr[3];
            spline_wf(a3, wib, fr);
            wibs[k] = wib;
            f01[k] = pack_u32(fr[0], fr[1]);
            f2u[k] = pack_u32(fr[2], 0.f);
            atomicAdd(&lh[wib], 1);
        }
    }
    __syncthreads();
    int v0 = 0;
    if (tid < 128) {
        v0 = (tid < KTOT) ? lh[tid] : 0;
        sb[tid] = v0;
    }
    __syncthreads();
    for (int off = 1; off < 128; off <<= 1) {
        int t = (tid >= off && tid < 128) ? sb[tid - off] : 0;
        __syncthreads();
        if (tid < 128) sb[tid] += t;
        __syncthreads();
    }
    if (tid < KTOT) lbase[tid] = sb[tid] - v0;
    __syncthreads();
#pragma unroll
    for (int k = 0; k < 8; ++k) {
        int e = base + tid + k * 256;
        if (e < E) {
            int w = wibs[k];
            int pos = base + lbase[w] + atomicAdd(&lrank[w], 1);
            uint4 rec = make_uint4((unsigned)src[e], f01[k], f2u[k], (unsigned)w);
            records[pos] = rec;
            int p = atomicAdd(&cursor[dst[e]], 1);
            iperm[pos] = p;
            records_d[p] = rec;
        }
    }
}

// all three f16 weight tables in one launch:
// Wh[wi*(Cin*Cout) + (i>>3)*(8*Cout) + o*8 + (i&7)] = W[wi][i][o]
__global__ void prep_all(const float* __restrict__ W2, const float* __restrict__ W3,
                         const float* __restrict__ W4, _Float16* __restrict__ wh2,
                         _Float16* __restrict__ wh3, _Float16* __restrict__ wh4) {
    int idx = blockIdx.x * blockDim.x + threadIdx.x;   // < 64000
    const float* W; _Float16* Wh; int Cin, Cout, r;
    if (idx < 16000)      { W = W2; Wh = wh2; Cin = 8;  Cout = 16; r = idx; }
    else if (idx < 48000) { W = W3; Wh = wh3; Cin = 16; Cout = 16; r = idx - 16000; }
    else if (idx < 64000) { W = W4; Wh = wh4; Cin = 16; Cout = 8;  r = idx - 48000; }
    else return;
    int wi = r / (Cin * Cout);
    int q = r % (Cin * Cout);
    int i = q / Cout, o = q % Cout;
    Wh[wi * (Cin * Cout) + (i >> 3) * (8 * Cout) + o * 8 + (i & 7)] = (_Float16)W[r];
}

// ---------- phase A: edge GEMM; reads f16 activations, writes y in dst-CSR order ----------
template<int Cin, int Cout>
__global__ __launch_bounds__(512) void edge_gemm(
        const uint4* __restrict__ records, const unsigned* __restrict__ xh,
        const _Float16* __restrict__ Wg, const int* __restrict__ iperm,
        _Float16* __restrict__ y, int E) {
    constexpr int SLOTS = 64 / Cout;
    constexpr int WH = KTOT * Cin * Cout;
    __shared__ __align__(16) _Float16 Wl[WH];
    for (int t = threadIdx.x; t < WH / 8; t += 512)
        ((uint4*)Wl)[t] = ((const uint4*)Wg)[t];
    __syncthreads();

    const int lane = threadIdx.x & 63;
    const int o = lane & (Cout - 1);
    const int slot = lane / Cout;
    const int wid = blockIdx.x * 8 + (threadIdx.x >> 6);
    const int stride = gridDim.x * 8;
    constexpr int TAP[8] = {0, 25, 5, 30, 1, 26, 6, 31};

    for (int base = wid * SLOTS; base < E; base += stride * SLOTS) {
        const int idx = base + slot;
        const bool act = idx < E;
        uint4 rec = act ? records[idx] : make_uint4(0u, 0u, 0u, 0u);
        int dpos = act ? iperm[idx] : 0;
        float bb[8];
        unpack_bb(rec.y, rec.z, bb);
        const int wib = (int)rec.w;

        h2 hx[Cin / 2];
        const uint4* xp = (const uint4*)(xh + (size_t)rec.x * (Cin / 2));
#pragma unroll
        for (int c = 0; c < Cin / 8; ++c) {
            uint4 q = xp[c];
            hx[4 * c + 0] = __builtin_bit_cast(h2, q.x);
            hx[4 * c + 1] = __builtin_bit_cast(h2, q.y);
            hx[4 * c + 2] = __builtin_bit_cast(h2, q.z);
            hx[4 * c + 3] = __builtin_bit_cast(h2, q.w);
        }
        float acc = 0.f;
#pragma unroll
        for (int t = 0; t < 8; ++t) {
            const int wi = wib + TAP[t];
            const _Float16* wp = &Wl[wi * (Cin * Cout) + o * 8];
            float dot = 0.f;
#pragma unroll
            for (int c = 0; c < Cin / 8; ++c) {
                union { uint4 u4; unsigned u[4]; } wu;
                wu.u4 = *(const uint4*)(wp + c * (8 * Cout));
                dot = fdot2f(hx[4 * c + 0], __builtin_bit_cast(h2, wu.u[0]), dot);
                dot = fdot2f(hx[4 * c + 1], __builtin_bit_cast(h2, wu.u[1]), dot);
                dot = fdot2f(hx[4 * c + 2], __builtin_bit_cast(h2, wu.u[2]), dot);
                dot = fdot2f(hx[4 * c + 3], __builtin_bit_cast(h2, wu.u[3]), dot);
            }
            acc = fmaf(bb[t], dot, acc);
        }
        if (act) y[(size_t)dpos * Cout + o] = (_Float16)acc;
    }
}

// ---------- phase B: sequential y reduce + root + ELU; writes f32 + packed f16 ----------
template<int Cin, int Cout>
__global__ void node_reduce(const int* __restrict__ rowptr,
                            const unsigned* __restrict__ yu,
                            const float* __restrict__ x,
                            const float* __restrict__ root,
                            const float* __restrict__ bias,
                            float* __restrict__ out, unsigned* __restrict__ xh,
                            int N) {
    constexpr int C2 = Cout / 2;
    int t = blockIdx.x * blockDim.x + threadIdx.x;
    int v = t / C2, o2 = t % C2;
    if (v >= N) return;
    int beg = rowptr[v], end = rowptr[v + 1];
    float a0 = 0.f, a1 = 0.f;
    for (int p = beg; p < end; ++p) {
        h2 hh = __builtin_bit_cast(h2, yu[(size_t)p * C2 + o2]);
        a0 += (float)hh[0];
        a1 += (float)hh[1];
    }
    const int o = 2 * o2;
    a0 += bias[o]; a1 += bias[o + 1];
#pragma unroll
    for (int i = 0; i < Cin; ++i) {
        float xv = x[(size_t)v * Cin + i];
        a0 = fmaf(xv, root[i * Cout + o], a0);
        a1 = fmaf(xv, root[i * Cout + o + 1], a1);
    }
    a0 = a0 > 0.f ? a0 : expm1f(a0);
    a1 = a1 > 0.f ? a1 : expm1f(a1);
    ((float2*)out)[(size_t)v * C2 + o2] = make_float2(a0, a1);
    xh[(size_t)v * C2 + o2] = pack_u32(a0, a1);
}

// ---------- fused small layers (records_d in dst-CSR order: contiguous reads) ----------

__global__ __launch_bounds__(512) void agg_l1(
        const int* __restrict__ rowptr, const uint4* __restrict__ records_d,
        const float* __restrict__ x, const float* __restrict__ W,
        const float* __restrict__ root, const float* __restrict__ bias,
        float* __restrict__ out, unsigned* __restrict__ xh2,
        int N, int totalWaves) {
    const int lane = threadIdx.x & 63;
    const int o = lane & 7;
    const int slot = lane >> 3;
    const int wid = blockIdx.x * 8 + (threadIdx.x >> 6);
    constexpr int TAP[8] = {0, 25, 5, 30, 1, 26, 6, 31};

    for (int v = wid; v < N; v += totalWaves) {
        const int beg = rowptr[v], end = rowptr[v + 1];
        float acc = 0.0f;
        for (int p0 = beg; p0 < end; p0 += 8) {
            const int p = p0 + slot;
            float xv = 0.f, bb[8];
            int wib = 0;
#pragma unroll
            for (int t = 0; t < 8; ++t) bb[t] = 0.f;
            if (p < end) {
                uint4 rec = records_d[p];
                unpack_bb(rec.y, rec.z, bb);
                wib = (int)rec.w;
                xv = x[rec.x];
            }
#pragma unroll
            for (int t = 0; t < 8; ++t)
                acc = fmaf(bb[t] * xv, __ldg(&W[(wib + TAP[t]) * 8 + o]), acc);
        }
#pragma unroll
        for (int m = 8; m < 64; m <<= 1) acc += __shfl_xor(acc, m);
        if (slot == 0) {
            float z = acc + bias[o] + x[v] * root[o];
            z = z > 0.0f ? z : expm1f(z);
            out[(size_t)v * 8 + o] = z;
            float zp = __shfl_xor(z, 1);
            if ((o & 1) == 0) xh2[(size_t)v * 4 + (o >> 1)] = pack_u32(z, zp);
        }
    }
}

__global__ __launch_bounds__(512) void agg_l5(
        const int* __restrict__ rowptr, const uint4* __restrict__ records_d,
        const float* __restrict__ x, const float* __restrict__ W,
        const float* __restrict__ root, const float* __restrict__ bias,
        float* __restrict__ out, int N, int totalWaves) {
    const int lane = threadIdx.x & 63;
    const int i = lane & 7;
    const int slot = lane >> 3;
    const int wid = blockIdx.x * 8 + (threadIdx.x >> 6);
    constexpr int TAP[8] = {0, 25, 5, 30, 1, 26, 6, 31};

    for (int v = wid; v < N; v += totalWaves) {
        const int beg = rowptr[v], end = rowptr[v + 1];
        float acc = 0.0f;
        for (int p0 = beg; p0 < end; p0 += 8) {
            const int p = p0 + slot;
            float xi = 0.f, bb[8];
            int wib = 0;
#pragma unroll
            for (int t = 0; t < 8; ++t) bb[t] = 0.f;
            if (p < end) {
                uint4 rec = records_d[p];
                unpack_bb(rec.y, rec.z, bb);
                wib = (int)rec.w;
                xi = x[(size_t)rec.x * 8 + i];
            }
#pragma unroll
            for (int t = 0; t < 8; ++t)
                acc = fmaf(bb[t] * xi, __ldg(&W[(wib + TAP[t]) * 8 + i]), acc);
        }
        if (slot == 0) acc = fmaf(x[(size_t)v * 8 + i], root[i], acc);
#pragma unroll
        for (int m = 1; m < 64; m <<= 1) acc += __shfl_xor(acc, m);
        if (lane == 0) {
            float z = acc + bias[0];
            out[v] = z > 0.0f ? z : expm1f(z);
        }
    }
}

// ---------- host ----------

static inline char* align256(char* p) {
    return (char*)(((uintptr_t)p + 255) & ~(uintptr_t)255);
}

extern "C" void kernel_launch(void* const* d_in, const int* in_sizes, int n_in,
                              void* d_out, int out_size, void* d_ws, size_t ws_size,
                              hipStream_t stream) {
    const float* x    = (const float*)d_in[0];
    const int*   ei   = (const int*)d_in[1];
    const float* attr = (const float*)d_in[2];
    const float* w[5]    = {(const float*)d_in[3],  (const float*)d_in[6],
                            (const float*)d_in[9],  (const float*)d_in[12],
                            (const float*)d_in[15]};
    const float* root[5] = {(const float*)d_in[4],  (const float*)d_in[7],
                            (const float*)d_in[10], (const float*)d_in[13],
                            (const float*)d_in[16]};
    const float* bias[5] = {(const float*)d_in[5],  (const float*)d_in[8],
                            (const float*)d_in[11], (const float*)d_in[14],
                            (const float*)d_in[17]};

    const int N = in_sizes[0];
    const int E = in_sizes[1] / 2;
    const int* src = ei;
    const int* dst = ei + E;

    char* ws = (char*)d_ws;
    float* bufA      = (float*)ws;    ws = align256(ws + (size_t)N * 16 * 4);
    float* bufB      = (float*)ws;    ws = align256(ws + (size_t)N * 16 * 4);
    int*   counts    = (int*)ws;      ws = align256(ws + (size_t)N * 4);
    int*   cursor    = (int*)ws;      ws = align256(ws + (size_t)N * 4);
    int*   rowptr    = (int*)ws;      ws = align256(ws + (size_t)(N + 1) * 4);
    int*   bsums     = (int*)ws;      ws = align256(ws + 256 * 4);
    uint4* records   = (uint4*)ws;    ws = align256(ws + (size_t)E * 16);
    uint4* records_d = (uint4*)ws;    ws = align256(ws + (size_t)E * 16);
    int*   iperm     = (int*)ws;      ws = align256(ws + (size_t)E * 4);
    _Float16* y      = (_Float16*)ws; ws = align256(ws + (size_t)E * 16 * 2);
    unsigned* xhA    = (unsigned*)ws; ws = align256(ws + (size_t)N * 8 * 4);
    unsigned* xhB    = (unsigned*)ws; ws = align256(ws + (size_t)N * 8 * 4);
    _Float16* wh2    = (_Float16*)ws; ws = align256(ws + (size_t)KTOT * 8 * 16 * 2);
    _Float16* wh3    = (_Float16*)ws; ws = align256(ws + (size_t)KTOT * 16 * 16 * 2);
    _Float16* wh4    = (_Float16*)ws; ws = align256(ws + (size_t)KTOT * 16 * 8 * 2);

    const int B = 256;
    const int nb = cdiv(N, 256);
    const unsigned* yu = (const unsigned*)y;

    init_kernel<<<cdiv(N, B), B, 0, stream>>>(x, bufA, counts, N);
    hist_dst<<<cdiv(E, B), B, 0, stream>>>(dst, counts, E);
    scan_blocks<<<nb, 256, 0, stream>>>(counts, rowptr, bsums, N);
    add_offsets2<<<nb, 256, 0, stream>>>(rowptr, bsums, cursor, nb, N, E);
    edge_scatter<<<cdiv(E, CHUNK), 256, 0, stream>>>(src, dst, attr, cursor,
                                                     records, records_d, iperm, E);
    prep_all<<<cdiv(64000, B), B, 0, stream>>>(w[1], w[2], w[3], wh2, wh3, wh4);

    const int GB = 512, TW = GB * 8;

    // L1 (1->8), fused; writes f32 out + f16 xhA
    agg_l1<<<GB, 512, 0, stream>>>(rowptr, records_d, bufA, w[0],
                                   root[0], bias[0], bufB, xhA, N, TW);
    // L2 (8->16)
    edge_gemm<8, 16><<<1024, 512, 0, stream>>>(records, xhA, wh2, iperm, y, E);
    node_reduce<8, 16><<<cdiv(N * 8, B), B, 0, stream>>>(rowptr, yu, bufB,
                                                         root[1], bias[1], bufA, xhB, N);
    // L3 (16->16)
    edge_gemm<16, 16><<<512, 512, 0, stream>>>(records, xhB, wh3, iperm, y, E);
    node_reduce<16, 16><<<cdiv(N * 8, B), B, 0, stream>>>(rowptr, yu, bufA,
                                                          root[2], bias[2], bufB, xhA, N);
    // L4 (16->8)
    edge_gemm<16, 8><<<1024, 512, 0, stream>>>(records, xhA, wh4, iperm, y, E);
    node_reduce<16, 8><<<cdiv(N * 4, B), B, 0, stream>>>(rowptr, yu, bufB,
                                                         root[3], bias[3], bufA, xhB, N);
    // L5 (8->1), fused
    agg_l5<<<GB, 512, 0, stream>>>(rowptr, records_d, bufA, w[4],
                                   root[4], bias[4], (float*)d_out, N, TW);
}

// Round 9
// 204.404 us; speedup vs baseline: 5.2714x; 1.0227x over previous
//
#include <hip/hip_runtime.h>
#include <math.h>

#define KSIZE 5
#define KTOT 125
#define CHUNK 2048

static constexpr float LOWER_CURV = -0.22703196f;
static constexpr float UPPER_CURV = 0.36853024f;

typedef _Float16 h2 __attribute__((ext_vector_type(2)));

__device__ __forceinline__ unsigned pack_u32(float a, float b) {
    return __builtin_bit_cast(unsigned, __builtin_amdgcn_cvt_pkrtz(a, b));
}
__device__ __forceinline__ float fdot2f(h2 a, h2 b, float c) {
#if __has_builtin(__builtin_amdgcn_fdot2)
    return __builtin_amdgcn_fdot2(a, b, c, false);
#else
    return c + (float)a[0] * (float)b[0] + (float)a[1] * (float)b[1];
#endif
}

static inline int cdiv(int a, int b) { return (a + b - 1) / b; }

// basis from 10-bit quantized fractions; bb[t] matches TAP[t]
__device__ __forceinline__ void unpack_bb10(unsigned w1, float bb[8]) {
    const float s = 1.0f / 1023.0f;
    float f0 = (float)(w1 & 1023u) * s;
    float f1 = (float)((w1 >> 10) & 1023u) * s;
    float f2 = (float)((w1 >> 20) & 1023u) * s;
    float a0 = 1.f - f0, a1 = 1.f - f1, a2 = 1.f - f2;
    float p00 = a0 * a1, p10 = f0 * a1, p01 = a0 * f1, p11 = f0 * f1;
    bb[0] = p00 * a2; bb[1] = p10 * a2; bb[2] = p01 * a2; bb[3] = p11 * a2;
    bb[4] = p00 * f2; bb[5] = p10 * f2; bb[6] = p01 * f2; bb[7] = p11 * f2;
}

__device__ __forceinline__ void spline_wf(const float* __restrict__ a3,
                                          int& wib, float fr[3]) {
    int k[3];
#pragma unroll
    for (int d = 0; d < 3; ++d) {
        float p = fminf(fmaxf(a3[d], 0.f), 1.f) * 4.f;
        float f0 = fminf(floorf(p), 3.f);
        k[d] = (int)f0;
        fr[d] = p - f0;
    }
    wib = k[0] * 25 + k[1] * 5 + k[2];
}

// ---------- preamble kernels ----------

// dst histogram (counts pre-zeroed by memset) + x transform, one launch
__global__ void hist_tr(const float* __restrict__ x, float* __restrict__ h,
                        const int* __restrict__ dst, int* __restrict__ counts,
                        int N, int E) {
    int i = blockIdx.x * blockDim.x + threadIdx.x;
    if (i < E) atomicAdd(&counts[dst[i]], 1);
    if (i < N) {
        float t = (x[i] - LOWER_CURV) / (UPPER_CURV - LOWER_CURV) * 20.0f - 10.0f;
        h[i] = fminf(fmaxf(t, -10.0f), 10.0f);
    }
}

__global__ void scan_blocks(const int* __restrict__ counts, int* __restrict__ rowptr,
                            int* __restrict__ bsums, int n) {
    __shared__ int sh[256];
    int tid = threadIdx.x;
    int i = blockIdx.x * 256 + tid;
    int v = (i < n) ? counts[i] : 0;
    sh[tid] = v;
    __syncthreads();
    for (int off = 1; off < 256; off <<= 1) {
        int t = (tid >= off) ? sh[tid - off] : 0;
        __syncthreads();
        sh[tid] += t;
        __syncthreads();
    }
    if (i < n) rowptr[i] = sh[tid] - v;
    if (tid == 255) bsums[blockIdx.x] = sh[255];
}

// per-block redundant scan of bsums, then offset rowptr & init cursor (1 launch)
__global__ void add_offsets2(int* __restrict__ rowptr, const int* __restrict__ bsums,
                             int* __restrict__ cursor, int nb, int n, int E) {
    __shared__ int sh[256];
    int tid = threadIdx.x;
    int v = (tid < nb) ? bsums[tid] : 0;
    sh[tid] = v;
    __syncthreads();
    for (int off = 1; off < 256; off <<= 1) {
        int t = (tid >= off) ? sh[tid - off] : 0;
        __syncthreads();
        sh[tid] += t;
        __syncthreads();
    }
    int boff = (blockIdx.x == 0) ? 0 : sh[blockIdx.x - 1];
    int i = blockIdx.x * 256 + tid;
    if (i < n) {
        int r = rowptr[i] + boff;
        rowptr[i] = r;
        cursor[i] = r;
    }
    if (i == 0) rowptr[n] = E;
}

// chunk-local counting sort by wib (blocks < nchunk) + f16 weight-table prep
// (tail blocks). Records are 8B: w0 = src | wib<<18; w1 = q0|q1<<10|q2<<20.
__global__ __launch_bounds__(256) void scatter_prep(
        const int* __restrict__ src, const int* __restrict__ dst,
        const float* __restrict__ attr, int* __restrict__ cursor,
        uint2* __restrict__ records, uint2* __restrict__ records_d,
        int* __restrict__ iperm, int E, int nchunk,
        const float* __restrict__ W2, const float* __restrict__ W3,
        const float* __restrict__ W4, _Float16* __restrict__ wh2,
        _Float16* __restrict__ wh3, _Float16* __restrict__ wh4) {
    __shared__ int lh[KTOT], lbase[KTOT], lrank[KTOT];
    __shared__ int sb[128];
    const int tid = threadIdx.x;

    if ((int)blockIdx.x >= nchunk) {
        // ---- weight prep path: Wh[wi][(i>>3)][o][i&7] = W[wi][i][o] ----
        int idx = ((int)blockIdx.x - nchunk) * 256 + tid;   // < 64000
        const float* W; _Float16* Wh; int Cin, Cout, r;
        if (idx < 16000)      { W = W2; Wh = wh2; Cin = 8;  Cout = 16; r = idx; }
        else if (idx < 48000) { W = W3; Wh = wh3; Cin = 16; Cout = 16; r = idx - 16000; }
        else                  { W = W4; Wh = wh4; Cin = 16; Cout = 8;  r = idx - 48000; }
        int wi = r / (Cin * Cout);
        int q = r % (Cin * Cout);
        int i = q / Cout, o = q % Cout;
        Wh[wi * (Cin * Cout) + (i >> 3) * (8 * Cout) + o * 8 + (i & 7)] = (_Float16)W[r];
        return;
    }

    for (int i = tid; i < KTOT; i += 256) { lh[i] = 0; lrank[i] = 0; }
    __syncthreads();
    const int base = blockIdx.x * CHUNK;

    int wibs[8]; unsigned w1s[8];
#pragma unroll
    for (int k = 0; k < 8; ++k) {
        int e = base + tid + k * 256;
        wibs[k] = -1;
        if (e < E) {
            float a3[3] = {attr[e * 3], attr[e * 3 + 1], attr[e * 3 + 2]};
            int wib; float fr[3];
            spline_wf(a3, wib, fr);
            wibs[k] = wib;
            unsigned q0 = (unsigned)__float2int_rn(fr[0] * 1023.f);
            unsigned q1 = (unsigned)__float2int_rn(fr[1] * 1023.f);
            unsigned q2 = (unsigned)__float2int_rn(fr[2] * 1023.f);
            w1s[k] = q0 | (q1 << 10) | (q2 << 20);
            atomicAdd(&lh[wib], 1);
        }
    }
    __syncthreads();
    int v0 = 0;
    if (tid < 128) {
        v0 = (tid < KTOT) ? lh[tid] : 0;
        sb[tid] = v0;
    }
    __syncthreads();
    for (int off = 1; off < 128; off <<= 1) {
        int t = (tid >= off && tid < 128) ? sb[tid - off] : 0;
        __syncthreads();
        if (tid < 128) sb[tid] += t;
        __syncthreads();
    }
    if (tid < KTOT) lbase[tid] = sb[tid] - v0;
    __syncthreads();
#pragma unroll
    for (int k = 0; k < 8; ++k) {
        int e = base + tid + k * 256;
        if (e < E) {
            int w = wibs[k];
            int pos = base + lbase[w] + atomicAdd(&lrank[w], 1);
            uint2 rec = make_uint2((unsigned)src[e] | ((unsigned)w << 18), w1s[k]);
            records[pos] = rec;
            int p = atomicAdd(&cursor[dst[e]], 1);
            iperm[pos] = p;
            records_d[p] = rec;
        }
    }
}

// ---------- phase A: edge GEMM; reads f16 activations, writes y in dst-CSR order ----------
template<int Cin, int Cout>
__global__ __launch_bounds__(512) void edge_gemm(
        const uint2* __restrict__ records, const unsigned* __restrict__ xh,
        const _Float16* __restrict__ Wg, const int* __restrict__ iperm,
        _Float16* __restrict__ y, int E) {
    constexpr int SLOTS = 64 / Cout;
    constexpr int WH = KTOT * Cin * Cout;
    __shared__ __align__(16) _Float16 Wl[WH];
    for (int t = threadIdx.x; t < WH / 8; t += 512)
        ((uint4*)Wl)[t] = ((const uint4*)Wg)[t];
    __syncthreads();

    const int lane = threadIdx.x & 63;
    const int o = lane & (Cout - 1);
    const int slot = lane / Cout;
    const int wid = blockIdx.x * 8 + (threadIdx.x >> 6);
    const int stride = gridDim.x * 8;
    constexpr int TAP[8] = {0, 25, 5, 30, 1, 26, 6, 31};

    for (int base = wid * SLOTS; base < E; base += stride * SLOTS) {
        const int idx = base + slot;
        const bool act = idx < E;
        uint2 rec = act ? records[idx] : make_uint2(0u, 0u);
        int dpos = act ? iperm[idx] : 0;
        float bb[8];
        unpack_bb10(rec.y, bb);
        const int wib = (int)(rec.x >> 18);
        const unsigned sn = rec.x & 0x3FFFFu;

        h2 hx[Cin / 2];
        const uint4* xp = (const uint4*)(xh + (size_t)sn * (Cin / 2));
#pragma unroll
        for (int c = 0; c < Cin / 8; ++c) {
            uint4 q = xp[c];
            hx[4 * c + 0] = __builtin_bit_cast(h2, q.x);
            hx[4 * c + 1] = __builtin_bit_cast(h2, q.y);
            hx[4 * c + 2] = __builtin_bit_cast(h2, q.z);
            hx[4 * c + 3] = __builtin_bit_cast(h2, q.w);
        }
        float acc = 0.f;
#pragma unroll
        for (int t = 0; t < 8; ++t) {
            const int wi = wib + TAP[t];
            const _Float16* wp = &Wl[wi * (Cin * Cout) + o * 8];
            float dot = 0.f;
#pragma unroll
            for (int c = 0; c < Cin / 8; ++c) {
                union { uint4 u4; unsigned u[4]; } wu;
                wu.u4 = *(const uint4*)(wp + c * (8 * Cout));
                dot = fdot2f(hx[4 * c + 0], __builtin_bit_cast(h2, wu.u[0]), dot);
                dot = fdot2f(hx[4 * c + 1], __builtin_bit_cast(h2, wu.u[1]), dot);
                dot = fdot2f(hx[4 * c + 2], __builtin_bit_cast(h2, wu.u[2]), dot);
                dot = fdot2f(hx[4 * c + 3], __builtin_bit_cast(h2, wu.u[3]), dot);
            }
            acc = fmaf(bb[t], dot, acc);
        }
        if (act) y[(size_t)dpos * Cout + o] = (_Float16)acc;
    }
}

// ---------- phase B: sequential y reduce + root + ELU; writes f32 + packed f16 ----------
template<int Cin, int Cout>
__global__ void node_reduce(const int* __restrict__ rowptr,
                            const unsigned* __restrict__ yu,
                            const float* __restrict__ x,
                            const float* __restrict__ root,
                            const float* __restrict__ bias,
                            float* __restrict__ out, unsigned* __restrict__ xh,
                            int N) {
    constexpr int C2 = Cout / 2;
    int t = blockIdx.x * blockDim.x + threadIdx.x;
    int v = t / C2, o2 = t % C2;
    if (v >= N) return;
    int beg = rowptr[v], end = rowptr[v + 1];
    float a0 = 0.f, a1 = 0.f;
    for (int p = beg; p < end; ++p) {
        h2 hh = __builtin_bit_cast(h2, yu[(size_t)p * C2 + o2]);
        a0 += (float)hh[0];
        a1 += (float)hh[1];
    }
    const int o = 2 * o2;
    a0 += bias[o]; a1 += bias[o + 1];
#pragma unroll
    for (int i = 0; i < Cin; ++i) {
        float xv = x[(size_t)v * Cin + i];
        a0 = fmaf(xv, root[i * Cout + o], a0);
        a1 = fmaf(xv, root[i * Cout + o + 1], a1);
    }
    a0 = a0 > 0.f ? a0 : expm1f(a0);
    a1 = a1 > 0.f ? a1 : expm1f(a1);
    ((float2*)out)[(size_t)v * C2 + o2] = make_float2(a0, a1);
    xh[(size_t)v * C2 + o2] = pack_u32(a0, a1);
}

// ---------- fused small layers (records_d in dst-CSR order: contiguous reads) ----------

__global__ __launch_bounds__(512) void agg_l1(
        const int* __restrict__ rowptr, const uint2* __restrict__ records_d,
        const float* __restrict__ x, const float* __restrict__ W,
        const float* __restrict__ root, const float* __restrict__ bias,
        float* __restrict__ out, unsigned* __restrict__ xh2,
        int N, int totalWaves) {
    const int lane = threadIdx.x & 63;
    const int o = lane & 7;
    const int slot = lane >> 3;
    const int wid = blockIdx.x * 8 + (threadIdx.x >> 6);
    constexpr int TAP[8] = {0, 25, 5, 30, 1, 26, 6, 31};

    for (int v = wid; v < N; v += totalWaves) {
        const int beg = rowptr[v], end = rowptr[v + 1];
        float acc = 0.0f;
        for (int p0 = beg; p0 < end; p0 += 8) {
            const int p = p0 + slot;
            float xv = 0.f, bb[8];
            int wib = 0;
#pragma unroll
            for (int t = 0; t < 8; ++t) bb[t] = 0.f;
            if (p < end) {
                uint2 rec = records_d[p];
                unpack_bb10(rec.y, bb);
                wib = (int)(rec.x >> 18);
                xv = x[rec.x & 0x3FFFFu];
            }
#pragma unroll
            for (int t = 0; t < 8; ++t)
                acc = fmaf(bb[t] * xv, __ldg(&W[(wib + TAP[t]) * 8 + o]), acc);
        }
#pragma unroll
        for (int m = 8; m < 64; m <<= 1) acc += __shfl_xor(acc, m);
        if (slot == 0) {
            float z = acc + bias[o] + x[v] * root[o];
            z = z > 0.0f ? z : expm1f(z);
            out[(size_t)v * 8 + o] = z;
            float zp = __shfl_xor(z, 1);
            if ((o & 1) == 0) xh2[(size_t)v * 4 + (o >> 1)] = pack_u32(z, zp);
        }
    }
}

__global__ __launch_bounds__(512) void agg_l5(
        const int* __restrict__ rowptr, const uint2* __restrict__ records_d,
        const float* __restrict__ x, const float* __restrict__ W,
        const float* __restrict__ root, const float* __restrict__ bias,
        float* __restrict__ out, int N, int totalWaves) {
    const int lane = threadIdx.x & 63;
    const int i = lane & 7;
    const int slot = lane >> 3;
    const int wid = blockIdx.x * 8 + (threadIdx.x >> 6);
    constexpr int TAP[8] = {0, 25, 5, 30, 1, 26, 6, 31};

    for (int v = wid; v < N; v += totalWaves) {
        const int beg = rowptr[v], end = rowptr[v + 1];
        float acc = 0.0f;
        for (int p0 = beg; p0 < end; p0 += 8) {
            const int p = p0 + slot;
            float xi = 0.f, bb[8];
            int wib = 0;
#pragma unroll
            for (int t = 0; t < 8; ++t) bb[t] = 0.f;
            if (p < end) {
                uint2 rec = records_d[p];
                unpack_bb10(rec.y, bb);
                wib = (int)(rec.x >> 18);
                xi = x[(size_t)(rec.x & 0x3FFFFu) * 8 + i];
            }
#pragma unroll
            for (int t = 0; t < 8; ++t)
                acc = fmaf(bb[t] * xi, __ldg(&W[(wib + TAP[t]) * 8 + i]), acc);
        }
        if (slot == 0) acc = fmaf(x[(size_t)v * 8 + i], root[i], acc);
#pragma unroll
        for (int m = 1; m < 64; m <<= 1) acc += __shfl_xor(acc, m);
        if (lane == 0) {
            float z = acc + bias[0];
            out[v] = z > 0.0f ? z : expm1f(z);
        }
    }
}

// ---------- host ----------

static inline char* align256(char* p) {
    return (char*)(((uintptr_t)p + 255) & ~(uintptr_t)255);
}

extern "C" void kernel_launch(void* const* d_in, const int* in_sizes, int n_in,
                              void* d_out, int out_size, void* d_ws, size_t ws_size,
                              hipStream_t stream) {
    const float* x    = (const float*)d_in[0];
    const int*   ei   = (const int*)d_in[1];
    const float* attr = (const float*)d_in[2];
    const float* w[5]    = {(const float*)d_in[3],  (const float*)d_in[6],
                            (const float*)d_in[9],  (const float*)d_in[12],
                            (const float*)d_in[15]};
    const float* root[5] = {(const float*)d_in[4],  (const float*)d_in[7],
                            (const float*)d_in[10], (const float*)d_in[13],
                            (const float*)d_in[16]};
    const float* bias[5] = {(const float*)d_in[5],  (const float*)d_in[8],
                            (const float*)d_in[11], (const float*)d_in[14],
                            (const float*)d_in[17]};

    const int N = in_sizes[0];
    const int E = in_sizes[1] / 2;
    const int* src = ei;
    const int* dst = ei + E;

    char* ws = (char*)d_ws;
    float* bufA      = (float*)ws;    ws = align256(ws + (size_t)N * 16 * 4);
    float* bufB      = (float*)ws;    ws = align256(ws + (size_t)N * 16 * 4);
    int*   counts    = (int*)ws;      ws = align256(ws + (size_t)N * 4);
    int*   cursor    = (int*)ws;      ws = align256(ws + (size_t)N * 4);
    int*   rowptr    = (int*)ws;      ws = align256(ws + (size_t)(N + 1) * 4);
    int*   bsums     = (int*)ws;      ws = align256(ws + 256 * 4);
    uint2* records   = (uint2*)ws;    ws = align256(ws + (size_t)E * 8);
    uint2* records_d = (uint2*)ws;    ws = align256(ws + (size_t)E * 8);
    int*   iperm     = (int*)ws;      ws = align256(ws + (size_t)E * 4);
    _Float16* y      = (_Float16*)ws; ws = align256(ws + (size_t)E * 16 * 2);
    unsigned* xhA    = (unsigned*)ws; ws = align256(ws + (size_t)N * 8 * 4);
    unsigned* xhB    = (unsigned*)ws; ws = align256(ws + (size_t)N * 8 * 4);
    _Float16* wh2    = (_Float16*)ws; ws = align256(ws + (size_t)KTOT * 8 * 16 * 2);
    _Float16* wh3    = (_Float16*)ws; ws = align256(ws + (size_t)KTOT * 16 * 16 * 2);
    _Float16* wh4    = (_Float16*)ws; ws = align256(ws + (size_t)KTOT * 16 * 8 * 2);

    const int B = 256;
    const int nb = cdiv(N, 256);
    const int nchunk = cdiv(E, CHUNK);
    const int nprep = cdiv(64000, 256);
    const unsigned* yu = (const unsigned*)y;

    hipMemsetAsync(counts, 0, (size_t)N * 4, stream);
    hist_tr<<<cdiv(E, B), B, 0, stream>>>(x, bufA, dst, counts, N, E);
    scan_blocks<<<nb, 256, 0, stream>>>(counts, rowptr, bsums, N);
    add_offsets2<<<nb, 256, 0, stream>>>(rowptr, bsums, cursor, nb, N, E);
    scatter_prep<<<nchunk + nprep, 256, 0, stream>>>(
        src, dst, attr, cursor, records, records_d, iperm, E, nchunk,
        w[1], w[2], w[3], wh2, wh3, wh4);

    const int GB = 512, TW = GB * 8;

    // L1 (1->8), fused; writes f32 out + f16 xhA
    agg_l1<<<GB, 512, 0, stream>>>(rowptr, records_d, bufA, w[0],
                                   root[0], bias[0], bufB, xhA, N, TW);
    // L2 (8->16)
    edge_gemm<8, 16><<<1024, 512, 0, stream>>>(records, xhA, wh2, iperm, y, E);
    node_reduce<8, 16><<<cdiv(N * 8, B), B, 0, stream>>>(rowptr, yu, bufB,
                                                         root[1], bias[1], bufA, xhB, N);
    // L3 (16->16)
    edge_gemm<16, 16><<<512, 512, 0, stream>>>(records, xhB, wh3, iperm, y, E);
    node_reduce<16, 16><<<cdiv(N * 8, B), B, 0, stream>>>(rowptr, yu, bufA,
                                                          root[2], bias[2], bufB, xhA, N);
    // L4 (16->8)
    edge_gemm<16, 8><<<1024, 512, 0, stream>>>(records, xhA, wh4, iperm, y, E);
    node_reduce<16, 8><<<cdiv(N * 4, B), B, 0, stream>>>(rowptr, yu, bufB,
                                                         root[3], bias[3], bufA, xhB, N);
    // L5 (8->1), fused
    agg_l5<<<GB, 512, 0, stream>>>(rowptr, records_d, bufA, w[4],
                                   root[4], bias[4], (float*)d_out, N, TW);
}